// Round 8
// baseline (553.339 us; speedup 1.0000x reference)
//
#include <hip/hip_runtime.h>
#include <hip/hip_bf16.h>

// ValueNet: 7x SAGEConv(mean) + global_add_pool + MLP head.
// N=50000 nodes, E=600000 edges/set, H=128, G=64 graphs.
//
// out_i = mean_j(z_j) + bl + y_i,  z = h@Wl, y = h@Wr (linearity of mean).
// GEMM on MFMA bf16 with split precision (hi+lo planes, 3 MFMAs: hh+hl+lh).
// z,y stored bf16. h stored as hi/lo bf16 planes.
//
// R20: RACE-FREE FUSION agg(L)+gemm(L+1) per row-block (cooperative launch
//      is graph-capture-fatal, R19). gemm(L+1) needs only its own 64 rows
//      of agg(L) output -> block computes agg for its 64 nodes, writes h
//      hi/lo DIRECTLY into the gemm LDS tile (never to HBM), syncthreads,
//      runs the MFMA body. z/y double-buffered (ping-pong) so agg reads
//      pair A while gemm writes pair B -> no cross-block hazard, no grid
//      sync. Saves 51.2MB traffic + 1 boundary per fused layer (x6).
//      Bodies verbatim: R18 agg tree, R13 LDS-read gemm ([64][136] pad);
//      rows >= N clamp to node N-1 exactly like the old staging.
// R18: aggnorm 8-in-flight halves (v[8]); final layer keeps it.
// R17: k_prep = merged wsplit+split+zeroing.
// R14: gemm0 (from x) keeps global_load_lds(16B) staging.
// CSR build (R12): LDS-staged bucket sort, NO per-key global atomics.

constexpr int N_NODES = 50000;
constexpr int NE      = 600000;
constexpr int H       = 128;
constexpr int NG      = 64;
constexpr int N3      = 3 * N_NODES;            // 150000

constexpr int NB   = (N3 + 1023) >> 10;          // 147 buckets (1024 keys each)
constexpr int EPB  = 2048;                       // edges per block (phase A)
constexpr int BPS  = (NE + EPB - 1) / EPB;       // 293 blocks per edge set
constexpr int CAP2 = 19456;                      // slots/bucket (exp ~15.4k padded; mult of 8)

typedef __attribute__((ext_vector_type(8))) short short8;
typedef __attribute__((ext_vector_type(4))) float f32x4;

__device__ __forceinline__ ushort f2bf(float f) {  // RNE float->bf16
    uint x = __float_as_uint(f);
    return (ushort)((x + 0x7FFFu + ((x >> 16) & 1u)) >> 16);
}
__device__ __forceinline__ float bf2f(ushort u) {
    return __uint_as_float(((uint)u) << 16);
}

// ---------------- Phase A: LDS-staged bucketize (padded, sentinel-filled) ----------------

__global__ __launch_bounds__(256) void k_bucketize(
    const int* __restrict__ e0, const int* __restrict__ e1,
    const int* __restrict__ e2, int* __restrict__ gcnt,
    int* __restrict__ rcnt, int2* __restrict__ bucket) {
    __shared__ int hist[NB];
    __shared__ int basearr[NB];
    __shared__ int cur[NB];
    __shared__ int gposs[NB];
    __shared__ int2 stage[EPB];
    __shared__ int dstoff[EPB];

    int t = threadIdx.x;
    int s = blockIdx.x / BPS;
    int w = blockIdx.x - s * BPS;
    const int* ep = (s == 0 ? e0 : (s == 1 ? e1 : e2));
    int eBase = w * EPB;
    int m = NE - eBase;
    if (m > EPB) m = EPB;

    for (int i = t; i < NB; i += 256) hist[i] = 0;
    __syncthreads();

    // pass 1: read edges into regs, LDS histogram
    int myk[EPB / 256], mys[EPB / 256];
#pragma unroll
    for (int k = 0; k < EPB / 256; ++k) {
        int i = t + 256 * k;
        if (i < m) {
            int d   = ep[NE + eBase + i];
            int src = ep[eBase + i];
            int key = s * N_NODES + d;
            myk[k] = key; mys[k] = src;
            atomicAdd(&hist[key >> 10], 1);
        } else {
            myk[k] = -1;
        }
    }
    __syncthreads();

    if (t == 0) {  // serial scan over 147 entries (cheap)
        int run = 0;
        for (int b = 0; b < NB; ++b) { basearr[b] = run; run += hist[b]; }
    }
    __syncthreads();

    if (t < NB) {  // padded reserve: ONE atomic per (block,bucket); runs 64B-aligned
        int h = hist[t];
        int p = (h + 7) & ~7;
        gposs[t] = p ? atomicAdd(&gcnt[t], p) : 0;
        if (h) atomicAdd(&rcnt[t], h);
        cur[t] = 0;
    }
    __syncthreads();

    // pass 2: scatter into LDS stage in bucket order; record dense dst offsets
#pragma unroll
    for (int k = 0; k < EPB / 256; ++k) {
        if (myk[k] >= 0) {
            int b  = myk[k] >> 10;
            int sl = atomicAdd(&cur[b], 1);
            int p  = basearr[b] + sl;
            stage[p]  = make_int2(myk[k], mys[k]);
            dstoff[p] = b * CAP2 + gposs[b] + sl;
        }
    }
    __syncthreads();

    // copyout: consecutive stage slots within a run -> consecutive global addrs
    for (int i = t; i < m; i += 256) bucket[dstoff[i]] = stage[i];
    // sentinel-fill the pad slots (<=7 per (block,bucket), same lines as runs)
    for (int i = t; i < NB * 8; i += 256) {
        int b = i >> 3, j = i & 7;
        int h = hist[b];
        int p = (h + 7) & ~7;
        if (h + j < p)
            bucket[(size_t)b * CAP2 + gposs[b] + h + j] = make_int2(-1, 0);
    }
}

// ---------------- Phase B: per-bucket hist + scan -> ptr slice + adj scatter ----------------

__global__ __launch_bounds__(512) void k_scatter2(const int2* __restrict__ bucket,
                                                  const int* __restrict__ gcnt,
                                                  const int* __restrict__ rcnt,
                                                  int* __restrict__ ptr,
                                                  int* __restrict__ adj) {
    int b = blockIdx.x;           // 0..NB-1
    int base = b << 10;
    int nk = N3 - base;
    if (nk > 1024) nk = 1024;
    __shared__ int lh[1024];
    __shared__ int lsum[512];
    __shared__ int lfill[1024];
    __shared__ int bb;
    int t = threadIdx.x;

    // exclusive prefix of real bucket totals -> bb (value at index b only)
    int rv = (t < NB) ? rcnt[t] : 0;
    lsum[t] = rv;
    __syncthreads();
    for (int off = 1; off < 512; off <<= 1) {
        int u = (t >= off) ? lsum[t - off] : 0;
        __syncthreads();
        if (t >= off) lsum[t] += u;
        __syncthreads();
    }
    if (t == b) bb = lsum[t] - rv;
    if (b == 0 && t == 0) ptr[N3] = 3 * NE;
    for (int i = t; i < 1024; i += 512) lh[i] = 0;
    __syncthreads();

    int c = gcnt[b];              // padded slot count actually used
    const int2* seg = bucket + (size_t)b * CAP2;
    for (int i = t; i < c; i += 512) {
        int k = seg[i].x;
        if (k >= 0) atomicAdd(&lh[k - base], 1);
    }
    __syncthreads();
    // exclusive 1024-scan: 2 seq per thread + 512 Hillis-Steele
    int v0 = lh[t * 2], v1 = lh[t * 2 + 1];
    int ts = v0 + v1;
    lsum[t] = ts;
    __syncthreads();
    for (int off = 1; off < 512; off <<= 1) {
        int u = (t >= off) ? lsum[t - off] : 0;
        __syncthreads();
        if (t >= off) lsum[t] += u;
        __syncthreads();
    }
    int ex = lsum[t] - ts + bb;
    int e0 = ex, e1 = ex + v0;
    if (t * 2     < nk) { ptr[base + t * 2]     = e0; lfill[t * 2]     = e0; }
    if (t * 2 + 1 < nk) { ptr[base + t * 2 + 1] = e1; lfill[t * 2 + 1] = e1; }
    __syncthreads();
    for (int i = t; i < c; i += 512) {
        int2 ed = seg[i];
        if (ed.x >= 0) {
            int pos = atomicAdd(&lfill[ed.x - base], 1);
            adj[pos] = ed.y;
        }
    }
}

// ---------------- R17: merged prep = weight pre-scatter + x split + zeroing ----------------

__global__ void k_prep(const float* __restrict__ x, ushort* __restrict__ hi,
                       ushort* __restrict__ lo, int* __restrict__ zmem,
                       const float* W0l, const float* W0r, const float* W1l,
                       const float* W1r, const float* W2l, const float* W2r,
                       const float* W3l, const float* W3r, const float* W4l,
                       const float* W4r, ushort* __restrict__ Bpk) {
    int bid = blockIdx.x;
    int t   = threadIdx.x;
    if (bid < 640) {
        int idx = bid * 256 + t;  // 0..5*32768-1
        if (idx >= 5 * 32768) return;
        int c = idx >> 15, r = idx & 32767;
        const float* Wl = (c == 0 ? W0l : c == 1 ? W1l : c == 2 ? W2l : c == 3 ? W3l : W4l);
        const float* Wr = (c == 0 ? W0r : c == 1 ? W1r : c == 2 ? W2r : c == 3 ? W3r : W4r);
        int n = r & 255, k = r >> 8;
        float w = (n < H) ? Wl[k * H + n] : Wr[k * H + (n - H)];
        int q = k >> 5, g = (k >> 3) & 3, j = k & 7;
        int off = ((q * 4 + g) * 256 + n) * 8 + j;
        ushort h = f2bf(w);
        ushort* bh = Bpk + (size_t)c * 65536;
        bh[off]         = h;
        bh[32768 + off] = f2bf(w - bf2f(h));
        return;
    }
    int tid = (bid - 640) * 256 + t;
    if (tid < NG * H + 2 * NB) zmem[tid] = 0;   // gbuf + gcnt + rcnt
    size_t i = (size_t)tid * 4;
    if (i >= (size_t)N_NODES * H) return;
    float4 v = *(const float4*)(x + i);
    ushort4 h, l;
    h.x = f2bf(v.x); l.x = f2bf(v.x - bf2f(h.x));
    h.y = f2bf(v.y); l.y = f2bf(v.y - bf2f(h.y));
    h.z = f2bf(v.z); l.z = f2bf(v.z - bf2f(h.z));
    h.w = f2bf(v.w); l.w = f2bf(v.w - bf2f(h.w));
    *(ushort4*)(hi + i) = h;
    *(ushort4*)(lo + i) = l;
}

// ---------------- MFMA GEMM (layer 1 only, A = x planes): R14 staged ----------------

__global__ __launch_bounds__(256) void k_gemm_mfma(
    const ushort* __restrict__ Ahi, const ushort* __restrict__ Alo,
    const ushort* __restrict__ Bh, const ushort* __restrict__ Bl,
    ushort* __restrict__ z, ushort* __restrict__ yb) {
    __shared__ ushort AshF[2 * 64 * 128];   // 32 KB
    int t = threadIdx.x;
    int rowBase = blockIdx.x * 64;
    {
        int wslot = t & ~63;                 // wave-uniform slot base
        int lane  = t & 63;
#pragma unroll
        for (int i = 0; i < 8; ++i) {
            int sbase = i * 256 + wslot;     // wave's first slot this round
            int S     = sbase + lane;        // this lane's slot
            int plane = S >> 10;
            int row   = (S >> 4) & 63;
            int pc    = S & 15;
            int grow  = rowBase + row;
            if (grow > N_NODES - 1) grow = N_NODES - 1;
            const ushort* Ap  = plane ? Alo : Ahi;
            const ushort* src = Ap + (size_t)grow * H + ((pc ^ (row & 15)) << 3);
            ushort* ldst = AshF + (size_t)sbase * 8;   // wave-uniform; HW adds lane*16B
            __builtin_amdgcn_global_load_lds(
                (const __attribute__((address_space(1))) void*)src,
                (__attribute__((address_space(3))) void*)ldst, 16, 0, 0);
        }
    }
    __syncthreads();

    int wave = t >> 6, lane = t & 63;
    int m16 = lane & 15, q4 = lane >> 4;
    int n0 = wave * 64;

    f32x4 acc[4][4];
#pragma unroll
    for (int r = 0; r < 4; ++r)
#pragma unroll
        for (int c = 0; c < 4; ++c) {
            acc[r][c][0] = 0.f; acc[r][c][1] = 0.f;
            acc[r][c][2] = 0.f; acc[r][c][3] = 0.f;
        }

    for (int q = 0; q < 4; ++q) {
        short8 bh_[4], bl_[4], ah_[4], al_[4];
#pragma unroll
        for (int c = 0; c < 4; ++c) {
            int boff = ((q * 4 + q4) * 256 + n0 + c * 16 + m16) * 8;
            bh_[c] = *(const short8*)(Bh + boff);
            bl_[c] = *(const short8*)(Bl + boff);
        }
#pragma unroll
        for (int r = 0; r < 4; ++r) {
            int roff = ((r * 16 + m16) << 7) + (((q * 4 + q4) ^ m16) << 3);
            ah_[r] = *(const short8*)&AshF[roff];
            al_[r] = *(const short8*)&AshF[8192 + roff];
        }
#pragma unroll
        for (int r = 0; r < 4; ++r)
#pragma unroll
            for (int c = 0; c < 4; ++c) {
                acc[r][c] = __builtin_amdgcn_mfma_f32_16x16x32_bf16(
                    ah_[r], bh_[c], acc[r][c], 0, 0, 0);
                acc[r][c] = __builtin_amdgcn_mfma_f32_16x16x32_bf16(
                    ah_[r], bl_[c], acc[r][c], 0, 0, 0);
                acc[r][c] = __builtin_amdgcn_mfma_f32_16x16x32_bf16(
                    al_[r], bh_[c], acc[r][c], 0, 0, 0);
            }
    }

    // C/D layout: col=lane&15, row=(lane>>4)*4+reg (m89-verified)
#pragma unroll
    for (int r = 0; r < 4; ++r)
#pragma unroll
        for (int c = 0; c < 4; ++c) {
            int col = n0 + c * 16 + m16;
            ushort* op = (col < H) ? (z + col) : (yb + (col - H));
#pragma unroll
            for (int j = 0; j < 4; ++j) {
                int gr = rowBase + r * 16 + q4 * 4 + j;
                if (gr < N_NODES) op[(size_t)gr * H] = f2bf(acc[r][c][j]);
            }
        }
}

// ---------------- R20: fused agg(L) -> LDS -> gemm(L+1) per 64-row block ----------------
// agg body = R18 verbatim (8-in-flight halves); h hi/lo written to LDS tile
// only. gemm body = R13 LDS-read verbatim ([64][136] pad). Rows >= N clamp
// to node N-1 (matches old staging's grow clamp; C-write still guarded).

__global__ __launch_bounds__(256) void k_fused(
    const ushort* __restrict__ zin, const ushort* __restrict__ yin,
    ushort* __restrict__ zout, ushort* __restrict__ yout,
    const int* __restrict__ ptr, const int* __restrict__ adj,
    const float* __restrict__ bl,
    const ushort* __restrict__ Bh, const ushort* __restrict__ Blw,
    int norm) {
    __shared__ ushort Ash[2][64][136];   // 34.8 KB
    int t = threadIdx.x;
    int rowBase = blockIdx.x * 64;
    int sl = t & 15;
    int nic = t >> 4;                    // 0..15: node-in-chunk

    // ---- AGG phase (layer L): 4 chunks x 16 nodes ----
    for (int c4 = 0; c4 < 4; ++c4) {
        int row = c4 * 16 + nic;         // 0..63
        int node = rowBase + row;
        if (node > N_NODES - 1) node = N_NODES - 1;   // clamp (dup last row)
        int beg = ptr[node], end = ptr[node + 1];
        int deg = end - beg;
        const ushort* zrow = zin + sl * 8;
        float a[8];
#pragma unroll
        for (int k = 0; k < 8; ++k) a[k] = 0.f;

        for (int base = 0; base < deg; base += 16) {
            int m = deg - base;
            if (m > 16) m = 16;
            int idx = (sl < m) ? adj[beg + base + sl] : 0;
#pragma unroll
            for (int half = 0; half < 2; ++half) {
                int mh = m - half * 8;
                if (mh <= 0) continue;
                if (mh > 8) mh = 8;
                int hb = half * 8;
                short8 v[8];
#pragma unroll
                for (int jj = 0; jj < 8; ++jj) {
                    int nj = __shfl(idx, hb + jj, 16);
                    if (jj < mh) v[jj] = *(const short8*)(zrow + (size_t)nj * H);
                }
                if (mh == 8) {
#pragma unroll
                    for (int k = 0; k < 8; ++k)
                        a[k] += ((bf2f((ushort)v[0][k]) + bf2f((ushort)v[1][k])) +
                                 (bf2f((ushort)v[2][k]) + bf2f((ushort)v[3][k]))) +
                                ((bf2f((ushort)v[4][k]) + bf2f((ushort)v[5][k])) +
                                 (bf2f((ushort)v[6][k]) + bf2f((ushort)v[7][k])));
                } else if (mh >= 4) {
#pragma unroll
                    for (int k = 0; k < 8; ++k)
                        a[k] += (bf2f((ushort)v[0][k]) + bf2f((ushort)v[1][k])) +
                                (bf2f((ushort)v[2][k]) + bf2f((ushort)v[3][k]));
                    if (mh > 4) {
#pragma unroll
                        for (int k = 0; k < 8; ++k) a[k] += bf2f((ushort)v[4][k]);
                    }
                    if (mh > 5) {
#pragma unroll
                        for (int k = 0; k < 8; ++k) a[k] += bf2f((ushort)v[5][k]);
                    }
                    if (mh > 6) {
#pragma unroll
                        for (int k = 0; k < 8; ++k) a[k] += bf2f((ushort)v[6][k]);
                    }
                } else {
                    if (mh > 0) {
#pragma unroll
                        for (int k = 0; k < 8; ++k) a[k] += bf2f((ushort)v[0][k]);
                    }
                    if (mh > 1) {
#pragma unroll
                        for (int k = 0; k < 8; ++k) a[k] += bf2f((ushort)v[1][k]);
                    }
                    if (mh > 2) {
#pragma unroll
                        for (int k = 0; k < 8; ++k) a[k] += bf2f((ushort)v[2][k]);
                    }
                }
            }
        }

        float inv = 1.0f / (float)(deg > 1 ? deg : 1);
        short8 yv = *(const short8*)(yin + (size_t)node * H + sl * 8);
        float4 bva = *(const float4*)(bl + sl * 8);
        float4 bvb = *(const float4*)(bl + sl * 8 + 4);
        float vv[8];
        vv[0] = a[0] * inv + bva.x + bf2f((ushort)yv[0]);
        vv[1] = a[1] * inv + bva.y + bf2f((ushort)yv[1]);
        vv[2] = a[2] * inv + bva.z + bf2f((ushort)yv[2]);
        vv[3] = a[3] * inv + bva.w + bf2f((ushort)yv[3]);
        vv[4] = a[4] * inv + bvb.x + bf2f((ushort)yv[4]);
        vv[5] = a[5] * inv + bvb.y + bf2f((ushort)yv[5]);
        vv[6] = a[6] * inv + bvb.z + bf2f((ushort)yv[6]);
        vv[7] = a[7] * inv + bvb.w + bf2f((ushort)yv[7]);
        if (norm) {
            float ss = 0.f;
#pragma unroll
            for (int k = 0; k < 8; ++k) ss += vv[k] * vv[k];
#pragma unroll
            for (int mm = 1; mm < 16; mm <<= 1) ss += __shfl_xor(ss, mm, 16);
            float n2 = 1.0f / fmaxf(sqrtf(ss), 1e-12f);
#pragma unroll
            for (int k = 0; k < 8; ++k) vv[k] *= n2;
        }
        short8 ho, lo8;
#pragma unroll
        for (int k = 0; k < 8; ++k) {
            ushort hh = f2bf(vv[k]);
            ho[k]  = (short)hh;
            lo8[k] = (short)f2bf(vv[k] - bf2f(hh));
        }
        *(short8*)&Ash[0][row][sl * 8] = ho;     // h stays in LDS
        *(short8*)&Ash[1][row][sl * 8] = lo8;
    }
    __syncthreads();

    // ---- GEMM phase (layer L+1), R13 LDS-read body ----
    int wave = t >> 6, lane = t & 63;
    int m16 = lane & 15, q4 = lane >> 4;
    int n0 = wave * 64;

    f32x4 acc[4][4];
#pragma unroll
    for (int r = 0; r < 4; ++r)
#pragma unroll
        for (int c = 0; c < 4; ++c) {
            acc[r][c][0] = 0.f; acc[r][c][1] = 0.f;
            acc[r][c][2] = 0.f; acc[r][c][3] = 0.f;
        }

    for (int q = 0; q < 4; ++q) {
        short8 bh_[4], bl_[4], ah_[4], al_[4];
#pragma unroll
        for (int c = 0; c < 4; ++c) {
            int boff = ((q * 4 + q4) * 256 + n0 + c * 16 + m16) * 8;
            bh_[c] = *(const short8*)(Bh + boff);
            bl_[c] = *(const short8*)(Blw + boff);
        }
#pragma unroll
        for (int r = 0; r < 4; ++r) {
            ah_[r] = *(const short8*)&Ash[0][r * 16 + m16][q * 32 + q4 * 8];
            al_[r] = *(const short8*)&Ash[1][r * 16 + m16][q * 32 + q4 * 8];
        }
#pragma unroll
        for (int r = 0; r < 4; ++r)
#pragma unroll
            for (int c = 0; c < 4; ++c) {
                acc[r][c] = __builtin_amdgcn_mfma_f32_16x16x32_bf16(
                    ah_[r], bh_[c], acc[r][c], 0, 0, 0);
                acc[r][c] = __builtin_amdgcn_mfma_f32_16x16x32_bf16(
                    ah_[r], bl_[c], acc[r][c], 0, 0, 0);
                acc[r][c] = __builtin_amdgcn_mfma_f32_16x16x32_bf16(
                    al_[r], bh_[c], acc[r][c], 0, 0, 0);
            }
    }

    // C/D layout: col=lane&15, row=(lane>>4)*4+reg (m89-verified)
#pragma unroll
    for (int r = 0; r < 4; ++r)
#pragma unroll
        for (int c = 0; c < 4; ++c) {
            int col = n0 + c * 16 + m16;
            ushort* op = (col < H) ? (zout + col) : (yout + (col - H));
#pragma unroll
            for (int j = 0; j < 4; ++j) {
                int gr = rowBase + r * 16 + q4 * 4 + j;
                if (gr < N_NODES) op[(size_t)gr * H] = f2bf(acc[r][c][j]);
            }
        }
}

// ---------------- R18 gather + epilogue (final layer, writes h to global) ----------------

__global__ __launch_bounds__(256, 8) void k_aggnorm(
    const ushort* __restrict__ z, const ushort* __restrict__ yb,
    const int* __restrict__ ptr, const int* __restrict__ adj,
    const float* __restrict__ bl,
    ushort* __restrict__ hhi, ushort* __restrict__ hlo, int norm) {
    int gtid = blockIdx.x * blockDim.x + threadIdx.x;
    int node = gtid >> 4;                  // 16 lanes per node
    int sl   = threadIdx.x & 15;           // lane covers cols [sl*8, sl*8+8)
    if (node >= N_NODES) return;
    int beg = ptr[node], end = ptr[node + 1];
    int deg = end - beg;
    const ushort* zrow = z + sl * 8;
    float a[8];
#pragma unroll
    for (int k = 0; k < 8; ++k) a[k] = 0.f;

    for (int base = 0; base < deg; base += 16) {
        int m = deg - base;
        if (m > 16) m = 16;
        int idx = (sl < m) ? adj[beg + base + sl] : 0;
#pragma unroll
        for (int half = 0; half < 2; ++half) {
            int mh = m - half * 8;
            if (mh <= 0) continue;
            if (mh > 8) mh = 8;
            int hb = half * 8;
            short8 v[8];
#pragma unroll
            for (int jj = 0; jj < 8; ++jj) {
                int nj = __shfl(idx, hb + jj, 16);
                if (jj < mh) v[jj] = *(const short8*)(zrow + (size_t)nj * H);
            }
            if (mh == 8) {
#pragma unroll
                for (int k = 0; k < 8; ++k)
                    a[k] += ((bf2f((ushort)v[0][k]) + bf2f((ushort)v[1][k])) +
                             (bf2f((ushort)v[2][k]) + bf2f((ushort)v[3][k]))) +
                            ((bf2f((ushort)v[4][k]) + bf2f((ushort)v[5][k])) +
                             (bf2f((ushort)v[6][k]) + bf2f((ushort)v[7][k])));
            } else if (mh >= 4) {
#pragma unroll
                for (int k = 0; k < 8; ++k)
                    a[k] += (bf2f((ushort)v[0][k]) + bf2f((ushort)v[1][k])) +
                            (bf2f((ushort)v[2][k]) + bf2f((ushort)v[3][k]));
                if (mh > 4) {
#pragma unroll
                    for (int k = 0; k < 8; ++k) a[k] += bf2f((ushort)v[4][k]);
                }
                if (mh > 5) {
#pragma unroll
                    for (int k = 0; k < 8; ++k) a[k] += bf2f((ushort)v[5][k]);
                }
                if (mh > 6) {
#pragma unroll
                    for (int k = 0; k < 8; ++k) a[k] += bf2f((ushort)v[6][k]);
                }
            } else {
                if (mh > 0) {
#pragma unroll
                    for (int k = 0; k < 8; ++k) a[k] += bf2f((ushort)v[0][k]);
                }
                if (mh > 1) {
#pragma unroll
                    for (int k = 0; k < 8; ++k) a[k] += bf2f((ushort)v[1][k]);
                }
                if (mh > 2) {
#pragma unroll
                    for (int k = 0; k < 8; ++k) a[k] += bf2f((ushort)v[2][k]);
                }
            }
        }
    }

    float inv = 1.0f / (float)(deg > 1 ? deg : 1);
    short8 yv = *(const short8*)(yb + (size_t)node * H + sl * 8);
    float4 bva = *(const float4*)(bl + sl * 8);
    float4 bvb = *(const float4*)(bl + sl * 8 + 4);
    float vv[8];
    vv[0] = a[0] * inv + bva.x + bf2f((ushort)yv[0]);
    vv[1] = a[1] * inv + bva.y + bf2f((ushort)yv[1]);
    vv[2] = a[2] * inv + bva.z + bf2f((ushort)yv[2]);
    vv[3] = a[3] * inv + bva.w + bf2f((ushort)yv[3]);
    vv[4] = a[4] * inv + bvb.x + bf2f((ushort)yv[4]);
    vv[5] = a[5] * inv + bvb.y + bf2f((ushort)yv[5]);
    vv[6] = a[6] * inv + bvb.z + bf2f((ushort)yv[6]);
    vv[7] = a[7] * inv + bvb.w + bf2f((ushort)yv[7]);
    if (norm) {
        float ss = 0.f;
#pragma unroll
        for (int k = 0; k < 8; ++k) ss += vv[k] * vv[k];
#pragma unroll
        for (int mm = 1; mm < 16; mm <<= 1) ss += __shfl_xor(ss, mm, 16);
        float n2 = 1.0f / fmaxf(sqrtf(ss), 1e-12f);
#pragma unroll
        for (int k = 0; k < 8; ++k) vv[k] *= n2;
    }
    short8 ho, lo8;
#pragma unroll
    for (int k = 0; k < 8; ++k) {
        ushort hh = f2bf(vv[k]);
        ho[k]  = (short)hh;
        lo8[k] = (short)f2bf(vv[k] - bf2f(hh));
    }
    *(short8*)(hhi + (size_t)node * H + sl * 8) = ho;
    *(short8*)(hlo + (size_t)node * H + sl * 8) = lo8;
}

// ---------------- global add pool (batch sorted), h = hi + lo ----------------

constexpr int POOL_ROWS = 64;

__global__ void k_pool(const ushort* __restrict__ hhi, const ushort* __restrict__ hlo,
                       const int* __restrict__ batch, float* __restrict__ g) {
    int col = threadIdx.x;  // 0..127
    int r0 = blockIdx.x * POOL_ROWS;
    int r1 = r0 + POOL_ROWS;
    if (r1 > N_NODES) r1 = N_NODES;
    if (r0 >= N_NODES) return;
    float acc = 0.f;
    int cur = batch[r0];
    int r = r0;
    for (; r + 4 <= r1; r += 4) {
        float v0 = bf2f(hhi[(size_t)r * H + col])       + bf2f(hlo[(size_t)r * H + col]);
        float v1 = bf2f(hhi[(size_t)(r + 1) * H + col]) + bf2f(hlo[(size_t)(r + 1) * H + col]);
        float v2 = bf2f(hhi[(size_t)(r + 2) * H + col]) + bf2f(hlo[(size_t)(r + 2) * H + col]);
        float v3 = bf2f(hhi[(size_t)(r + 3) * H + col]) + bf2f(hlo[(size_t)(r + 3) * H + col]);
        int b3 = batch[r + 3];
        if (b3 == cur) {
            acc += (v0 + v1) + (v2 + v3);
        } else {
            int b0 = batch[r], b1 = batch[r + 1], b2 = batch[r + 2];
            if (b0 != cur) { atomicAdd(&g[cur * H + col], acc); acc = 0.f; cur = b0; }
            acc += v0;
            if (b1 != cur) { atomicAdd(&g[cur * H + col], acc); acc = 0.f; cur = b1; }
            acc += v1;
            if (b2 != cur) { atomicAdd(&g[cur * H + col], acc); acc = 0.f; cur = b2; }
            acc += v2;
            if (b3 != cur) { atomicAdd(&g[cur * H + col], acc); acc = 0.f; cur = b3; }
            acc += v3;
        }
    }
    for (; r < r1; ++r) {
        int b = batch[r];
        if (b != cur) { atomicAdd(&g[cur * H + col], acc); acc = 0.f; cur = b; }
        acc += bf2f(hhi[(size_t)r * H + col]) + bf2f(hlo[(size_t)r * H + col]);
    }
    atomicAdd(&g[cur * H + col], acc);
}

// ---------------- MLP head ----------------

__global__ void k_mlp(const float* __restrict__ g, const float* __restrict__ W0,
                      const float* __restrict__ b0, const float* __restrict__ W1,
                      const float* __restrict__ b1, const float* __restrict__ Wh,
                      const float* __restrict__ bh, float* __restrict__ out) {
    int gi = blockIdx.x;
    int t  = threadIdx.x;  // 0..127
    __shared__ float buf0[H];
    __shared__ float buf1[H];
    __shared__ float red[2];

    float acc = b0[t];
    for (int k = 0; k < H; ++k) acc += g[gi * H + k] * W0[k * H + t];
    buf0[t] = fmaxf(acc, 0.f);
    __syncthreads();

    acc = b1[t];
    for (int k = 0; k < H; ++k) acc += buf0[k] * W1[k * H + t];
    buf1[t] = fmaxf(acc, 0.f);
    __syncthreads();

    float p = buf1[t] * Wh[t];
    for (int m = 1; m < 64; m <<= 1) p += __shfl_xor(p, m, 64);
    if ((t & 63) == 0) red[t >> 6] = p;
    __syncthreads();
    if (t == 0) out[gi] = red[0] + red[1] + bh[0];
}

// ---------------- driver ----------------

extern "C" void kernel_launch(void* const* d_in, const int* in_sizes, int n_in,
                              void* d_out, int out_size, void* d_ws, size_t ws_size,
                              hipStream_t stream) {
    const float* x     = (const float*)d_in[0];
    const int*   eic   = (const int*)d_in[1];
    const int*   eid   = (const int*)d_in[2];
    const int*   eit   = (const int*)d_in[3];
    const int*   batch = (const int*)d_in[4];
    const float* cW[5][3];
    for (int c = 0; c < 5; ++c) {
        cW[c][0] = (const float*)d_in[5 + c * 3 + 0];  // Wl
        cW[c][1] = (const float*)d_in[5 + c * 3 + 1];  // bl
        cW[c][2] = (const float*)d_in[5 + c * 3 + 2];  // Wr
    }
    const float* l0_W = (const float*)d_in[20];
    const float* l0_b = (const float*)d_in[21];
    const float* l1_W = (const float*)d_in[22];
    const float* l1_b = (const float*)d_in[23];
    const float* hd_W = (const float*)d_in[24];
    const float* hd_b = (const float*)d_in[25];
    float* outp = (float*)d_out;

    const size_t NH = (size_t)N_NODES * H;
    ushort* Ahi = (ushort*)d_ws;
    ushort* Alo = Ahi + NH;
    ushort* zb0 = Alo + NH;                    // ping
    ushort* yb0 = zb0 + NH;
    ushort* zb1 = yb0 + NH;                    // pong
    ushort* yb1 = zb1 + NH;
    ushort* Bpk = yb1 + NH;                    // 5 convs x 2 planes x 32768
    float*  gbuf = (float*)(Bpk + 5 * 2 * 32768);
    int* gcnt = (int*)(gbuf + (size_t)NG * H);     // zeroed by k_prep
    int* rcnt = gcnt + NB;                         // zeroed by k_prep
    int* ptr_all = rcnt + NB;                      // N3+1 ints (persistent)
    int* adj_all = ptr_all + (N3 + 1);             // 3*NE ints (persistent)
    // CSR-build scratch inside zb0+yb0 (dead until gemm0, stream-ordered):
    //   bucket[NB*CAP2 int2] (64B-aligned at zb0) = 22.88 MB < 25.6MB
    int2* bucket = (int2*)zb0;

    dim3 b256(256);

    // merged prep: weight pre-scatter (blocks<640) + x split + zeroing
    k_prep<<<dim3(640 + (int)(NH / 1024)), b256, 0, stream>>>(
        x, Ahi, Alo, (int*)gbuf,
        cW[0][0], cW[0][2], cW[1][0], cW[1][2], cW[2][0], cW[2][2],
        cW[3][0], cW[3][2], cW[4][0], cW[4][2], Bpk);

    // CSR build: bucketize -> per-bucket (total-scan + ptr + scatter)
    k_bucketize<<<dim3(3 * BPS), b256, 0, stream>>>(eic, eid, eit, gcnt, rcnt, bucket);
    k_scatter2<<<dim3(NB), dim3(512), 0, stream>>>(bucket, gcnt, rcnt, ptr_all, adj_all);

    const int L_set[7]  = {1, 0, 0, 2, 1, 0, 0};
    const int L_conv[7] = {0, 1, 1, 2, 3, 4, 4};
    const int L_norm[7] = {1, 1, 1, 0, 1, 1, 1};

    dim3 gGemm((N_NODES + 63) / 64);         // 782
    dim3 gAgg((N_NODES * 16 + 255) / 256);   // 3125 (final layer only)

    // layer 1 GEMM from x planes -> pair0
    k_gemm_mfma<<<gGemm, b256, 0, stream>>>(Ahi, Alo, Bpk + (size_t)L_conv[0] * 65536,
                                            Bpk + (size_t)L_conv[0] * 65536 + 32768,
                                            zb0, yb0);

    // fused agg(L)+gemm(L+1), L=0..5, ping-pong z/y pairs
    for (int L = 0; L < 6; ++L) {
        ushort* zi = (L & 1) ? zb1 : zb0;
        ushort* yi = (L & 1) ? yb1 : yb0;
        ushort* zo = (L & 1) ? zb0 : zb1;
        ushort* yo = (L & 1) ? yb0 : yb1;
        const ushort* Bh = Bpk + (size_t)L_conv[L + 1] * 65536;
        const ushort* Bl = Bh + 32768;
        k_fused<<<gGemm, b256, 0, stream>>>(zi, yi, zo, yo,
                                            ptr_all + L_set[L] * N_NODES, adj_all,
                                            cW[L_conv[L]][1], Bh, Bl, L_norm[L]);
    }

    // final agg (L=6) reads pair0 (6 even), writes h hi/lo for pool
    k_aggnorm<<<gAgg, b256, 0, stream>>>(zb0, yb0, ptr_all + L_set[6] * N_NODES,
                                         adj_all, cW[L_conv[6]][1], Ahi, Alo,
                                         L_norm[6]);

    k_pool<<<dim3((N_NODES + POOL_ROWS - 1) / POOL_ROWS), dim3(H), 0, stream>>>(
        Ahi, Alo, batch, gbuf);
    k_mlp<<<dim3(NG), dim3(H), 0, stream>>>(gbuf, l0_W, l0_b, l1_W, l1_b, hd_W, hd_b,
                                            outp);
}

// Round 9
// 520.499 us; speedup vs baseline: 1.0631x; 1.0631x over previous
//
#include <hip/hip_runtime.h>
#include <hip/hip_bf16.h>

// ValueNet: 7x SAGEConv(mean) + global_add_pool + MLP head.
// N=50000 nodes, E=600000 edges/set, H=128, G=64 graphs.
//
// out_i = mean_j(z_j) + bl + y_i,  z = h@Wl, y = h@Wr (linearity of mean).
// GEMM on MFMA bf16 with split precision (hi+lo planes, 3 MFMAs: hh+hl+lh).
// z,y stored bf16. h stored as hi/lo bf16 planes.
//
// R21: REVERT R20 fusion (occupancy 14% killed gather concurrency; bytes
//      proven irrelevant for agg). GEMM epilogue: operand-SWAPPED MFMA
//      (mfma(B,A) -> D^T in regs; A/B 16x16x32 fragments are layout-
//      symmetric so register contents unchanged) => reg j = 4 CONSECUTIVE
//      COLS -> C-write is 16x ushort4 packed stores/thread instead of 64
//      scalar ushort stores (4x fewer VMEM insts in the epilogue tail).
//      Bit-identical numerics (same products, same add order).
// R18: aggnorm 8-in-flight halves (v[8]) + launch_bounds(256,8).
// R17: k_prep = merged wsplit+split+zeroing.
// R14: GEMM A-staging via global_load_lds(16B), XOR-swizzled source;
//      k_scatter2 at 512 threads.
// CSR build (R12): LDS-staged bucket sort, NO per-key global atomics.
//
// Agg floor note (R13-R20): ~36-40us/layer invariant to instructions, L2
// residency (FETCH 95->39MB: no change), ILP, occupancy, and fusion ->
// treated as an L2/L3 random-line request-rate floor. Do not re-attack
// without a new mechanism.

constexpr int N_NODES = 50000;
constexpr int NE      = 600000;
constexpr int H       = 128;
constexpr int NG      = 64;
constexpr int N3      = 3 * N_NODES;            // 150000

constexpr int NB   = (N3 + 1023) >> 10;          // 147 buckets (1024 keys each)
constexpr int EPB  = 2048;                       // edges per block (phase A)
constexpr int BPS  = (NE + EPB - 1) / EPB;       // 293 blocks per edge set
constexpr int CAP2 = 19456;                      // slots/bucket (exp ~15.4k padded; mult of 8)

typedef __attribute__((ext_vector_type(8))) short short8;
typedef __attribute__((ext_vector_type(4))) float f32x4;

__device__ __forceinline__ ushort f2bf(float f) {  // RNE float->bf16
    uint x = __float_as_uint(f);
    return (ushort)((x + 0x7FFFu + ((x >> 16) & 1u)) >> 16);
}
__device__ __forceinline__ float bf2f(ushort u) {
    return __uint_as_float(((uint)u) << 16);
}

// ---------------- Phase A: LDS-staged bucketize (padded, sentinel-filled) ----------------

__global__ __launch_bounds__(256) void k_bucketize(
    const int* __restrict__ e0, const int* __restrict__ e1,
    const int* __restrict__ e2, int* __restrict__ gcnt,
    int* __restrict__ rcnt, int2* __restrict__ bucket) {
    __shared__ int hist[NB];
    __shared__ int basearr[NB];
    __shared__ int cur[NB];
    __shared__ int gposs[NB];
    __shared__ int2 stage[EPB];
    __shared__ int dstoff[EPB];

    int t = threadIdx.x;
    int s = blockIdx.x / BPS;
    int w = blockIdx.x - s * BPS;
    const int* ep = (s == 0 ? e0 : (s == 1 ? e1 : e2));
    int eBase = w * EPB;
    int m = NE - eBase;
    if (m > EPB) m = EPB;

    for (int i = t; i < NB; i += 256) hist[i] = 0;
    __syncthreads();

    // pass 1: read edges into regs, LDS histogram
    int myk[EPB / 256], mys[EPB / 256];
#pragma unroll
    for (int k = 0; k < EPB / 256; ++k) {
        int i = t + 256 * k;
        if (i < m) {
            int d   = ep[NE + eBase + i];
            int src = ep[eBase + i];
            int key = s * N_NODES + d;
            myk[k] = key; mys[k] = src;
            atomicAdd(&hist[key >> 10], 1);
        } else {
            myk[k] = -1;
        }
    }
    __syncthreads();

    if (t == 0) {  // serial scan over 147 entries (cheap)
        int run = 0;
        for (int b = 0; b < NB; ++b) { basearr[b] = run; run += hist[b]; }
    }
    __syncthreads();

    if (t < NB) {  // padded reserve: ONE atomic per (block,bucket); runs 64B-aligned
        int h = hist[t];
        int p = (h + 7) & ~7;
        gposs[t] = p ? atomicAdd(&gcnt[t], p) : 0;
        if (h) atomicAdd(&rcnt[t], h);
        cur[t] = 0;
    }
    __syncthreads();

    // pass 2: scatter into LDS stage in bucket order; record dense dst offsets
#pragma unroll
    for (int k = 0; k < EPB / 256; ++k) {
        if (myk[k] >= 0) {
            int b  = myk[k] >> 10;
            int sl = atomicAdd(&cur[b], 1);
            int p  = basearr[b] + sl;
            stage[p]  = make_int2(myk[k], mys[k]);
            dstoff[p] = b * CAP2 + gposs[b] + sl;
        }
    }
    __syncthreads();

    // copyout: consecutive stage slots within a run -> consecutive global addrs
    for (int i = t; i < m; i += 256) bucket[dstoff[i]] = stage[i];
    // sentinel-fill the pad slots (<=7 per (block,bucket), same lines as runs)
    for (int i = t; i < NB * 8; i += 256) {
        int b = i >> 3, j = i & 7;
        int h = hist[b];
        int p = (h + 7) & ~7;
        if (h + j < p)
            bucket[(size_t)b * CAP2 + gposs[b] + h + j] = make_int2(-1, 0);
    }
}

// ---------------- Phase B: per-bucket hist + scan -> ptr slice + adj scatter ----------------

__global__ __launch_bounds__(512) void k_scatter2(const int2* __restrict__ bucket,
                                                  const int* __restrict__ gcnt,
                                                  const int* __restrict__ rcnt,
                                                  int* __restrict__ ptr,
                                                  int* __restrict__ adj) {
    int b = blockIdx.x;           // 0..NB-1
    int base = b << 10;
    int nk = N3 - base;
    if (nk > 1024) nk = 1024;
    __shared__ int lh[1024];
    __shared__ int lsum[512];
    __shared__ int lfill[1024];
    __shared__ int bb;
    int t = threadIdx.x;

    // exclusive prefix of real bucket totals -> bb (value at index b only)
    int rv = (t < NB) ? rcnt[t] : 0;
    lsum[t] = rv;
    __syncthreads();
    for (int off = 1; off < 512; off <<= 1) {
        int u = (t >= off) ? lsum[t - off] : 0;
        __syncthreads();
        if (t >= off) lsum[t] += u;
        __syncthreads();
    }
    if (t == b) bb = lsum[t] - rv;
    if (b == 0 && t == 0) ptr[N3] = 3 * NE;
    for (int i = t; i < 1024; i += 512) lh[i] = 0;
    __syncthreads();

    int c = gcnt[b];              // padded slot count actually used
    const int2* seg = bucket + (size_t)b * CAP2;
    for (int i = t; i < c; i += 512) {
        int k = seg[i].x;
        if (k >= 0) atomicAdd(&lh[k - base], 1);
    }
    __syncthreads();
    // exclusive 1024-scan: 2 seq per thread + 512 Hillis-Steele
    int v0 = lh[t * 2], v1 = lh[t * 2 + 1];
    int ts = v0 + v1;
    lsum[t] = ts;
    __syncthreads();
    for (int off = 1; off < 512; off <<= 1) {
        int u = (t >= off) ? lsum[t - off] : 0;
        __syncthreads();
        if (t >= off) lsum[t] += u;
        __syncthreads();
    }
    int ex = lsum[t] - ts + bb;
    int e0 = ex, e1 = ex + v0;
    if (t * 2     < nk) { ptr[base + t * 2]     = e0; lfill[t * 2]     = e0; }
    if (t * 2 + 1 < nk) { ptr[base + t * 2 + 1] = e1; lfill[t * 2 + 1] = e1; }
    __syncthreads();
    for (int i = t; i < c; i += 512) {
        int2 ed = seg[i];
        if (ed.x >= 0) {
            int pos = atomicAdd(&lfill[ed.x - base], 1);
            adj[pos] = ed.y;
        }
    }
}

// ---------------- R17: merged prep = weight pre-scatter + x split + zeroing ----------------

__global__ void k_prep(const float* __restrict__ x, ushort* __restrict__ hi,
                       ushort* __restrict__ lo, int* __restrict__ zmem,
                       const float* W0l, const float* W0r, const float* W1l,
                       const float* W1r, const float* W2l, const float* W2r,
                       const float* W3l, const float* W3r, const float* W4l,
                       const float* W4r, ushort* __restrict__ Bpk) {
    int bid = blockIdx.x;
    int t   = threadIdx.x;
    if (bid < 640) {
        int idx = bid * 256 + t;  // 0..5*32768-1
        if (idx >= 5 * 32768) return;
        int c = idx >> 15, r = idx & 32767;
        const float* Wl = (c == 0 ? W0l : c == 1 ? W1l : c == 2 ? W2l : c == 3 ? W3l : W4l);
        const float* Wr = (c == 0 ? W0r : c == 1 ? W1r : c == 2 ? W2r : c == 3 ? W3r : W4r);
        int n = r & 255, k = r >> 8;
        float w = (n < H) ? Wl[k * H + n] : Wr[k * H + (n - H)];
        int q = k >> 5, g = (k >> 3) & 3, j = k & 7;
        int off = ((q * 4 + g) * 256 + n) * 8 + j;
        ushort h = f2bf(w);
        ushort* bh = Bpk + (size_t)c * 65536;
        bh[off]         = h;
        bh[32768 + off] = f2bf(w - bf2f(h));
        return;
    }
    int tid = (bid - 640) * 256 + t;
    if (tid < NG * H + 2 * NB) zmem[tid] = 0;   // gbuf + gcnt + rcnt
    size_t i = (size_t)tid * 4;
    if (i >= (size_t)N_NODES * H) return;
    float4 v = *(const float4*)(x + i);
    ushort4 h, l;
    h.x = f2bf(v.x); l.x = f2bf(v.x - bf2f(h.x));
    h.y = f2bf(v.y); l.y = f2bf(v.y - bf2f(h.y));
    h.z = f2bf(v.z); l.z = f2bf(v.z - bf2f(h.z));
    h.w = f2bf(v.w); l.w = f2bf(v.w - bf2f(h.w));
    *(ushort4*)(hi + i) = h;
    *(ushort4*)(lo + i) = l;
}

// ---------------- MFMA GEMM: (z,y) = (Ahi+Alo) @ (Bhi+Blo) ----------------
// R14 staging: global_load_lds(16B), linear LDS dest, XOR-swizzled source.
// R21 epilogue: operand-swapped MFMA -> D^T in regs; A/B fragments of
// 16x16x32 are layout-symmetric (idx=lane&15, k=q*32+(lane>>4)*8+j for
// both), so the SAME registers feed the swapped slots. Result: lane&15 =
// row, (lane>>4)*4+reg = col -> reg j spans 4 consecutive cols -> packed
// ushort4 stores (16/thread instead of 64 scalar). Bit-identical values.

__global__ __launch_bounds__(256) void k_gemm_mfma(
    const ushort* __restrict__ Ahi, const ushort* __restrict__ Alo,
    const ushort* __restrict__ Bh, const ushort* __restrict__ Bl,
    ushort* __restrict__ z, ushort* __restrict__ yb) {
    __shared__ ushort AshF[2 * 64 * 128];   // 32 KB
    int t = threadIdx.x;
    int rowBase = blockIdx.x * 64;
    {
        int wslot = t & ~63;                 // wave-uniform slot base
        int lane  = t & 63;
#pragma unroll
        for (int i = 0; i < 8; ++i) {
            int sbase = i * 256 + wslot;     // wave's first slot this round
            int S     = sbase + lane;        // this lane's slot
            int plane = S >> 10;
            int row   = (S >> 4) & 63;
            int pc    = S & 15;
            int grow  = rowBase + row;
            if (grow > N_NODES - 1) grow = N_NODES - 1;
            const ushort* Ap  = plane ? Alo : Ahi;
            const ushort* src = Ap + (size_t)grow * H + ((pc ^ (row & 15)) << 3);
            ushort* ldst = AshF + (size_t)sbase * 8;   // wave-uniform; HW adds lane*16B
            __builtin_amdgcn_global_load_lds(
                (const __attribute__((address_space(1))) void*)src,
                (__attribute__((address_space(3))) void*)ldst, 16, 0, 0);
        }
    }
    __syncthreads();

    int wave = t >> 6, lane = t & 63;
    int m16 = lane & 15, q4 = lane >> 4;
    int n0 = wave * 64;

    f32x4 acc[4][4];
#pragma unroll
    for (int r = 0; r < 4; ++r)
#pragma unroll
        for (int c = 0; c < 4; ++c) {
            acc[r][c][0] = 0.f; acc[r][c][1] = 0.f;
            acc[r][c][2] = 0.f; acc[r][c][3] = 0.f;
        }

    for (int q = 0; q < 4; ++q) {
        short8 bh_[4], bl_[4], ah_[4], al_[4];
#pragma unroll
        for (int c = 0; c < 4; ++c) {
            int boff = ((q * 4 + q4) * 256 + n0 + c * 16 + m16) * 8;
            bh_[c] = *(const short8*)(Bh + boff);
            bl_[c] = *(const short8*)(Bl + boff);
        }
#pragma unroll
        for (int r = 0; r < 4; ++r) {
            int roff = ((r * 16 + m16) << 7) + (((q * 4 + q4) ^ m16) << 3);
            ah_[r] = *(const short8*)&AshF[roff];
            al_[r] = *(const short8*)&AshF[8192 + roff];
        }
        // operand-swapped: mfma(B,A) accumulates D^T; same products, same
        // pass order as the original (ah,bh),(ah,bl),(al,bh).
#pragma unroll
        for (int r = 0; r < 4; ++r)
#pragma unroll
            for (int c = 0; c < 4; ++c) {
                acc[r][c] = __builtin_amdgcn_mfma_f32_16x16x32_bf16(
                    bh_[c], ah_[r], acc[r][c], 0, 0, 0);
                acc[r][c] = __builtin_amdgcn_mfma_f32_16x16x32_bf16(
                    bl_[c], ah_[r], acc[r][c], 0, 0, 0);
                acc[r][c] = __builtin_amdgcn_mfma_f32_16x16x32_bf16(
                    bh_[c], al_[r], acc[r][c], 0, 0, 0);
            }
    }

    // D^T layout: row = r*16 + (lane&15), col = n0 + c*16 + (lane>>4)*4 + j
    // -> 4 consecutive cols per reg quad -> packed 8B stores.
#pragma unroll
    for (int r = 0; r < 4; ++r) {
        int grow = rowBase + r * 16 + m16;
        if (grow >= N_NODES) continue;
#pragma unroll
        for (int c = 0; c < 4; ++c) {
            int colb = n0 + c * 16 + q4 * 4;   // 16-col tile never straddles H
            ushort4 pk;
            pk.x = f2bf(acc[r][c][0]);
            pk.y = f2bf(acc[r][c][1]);
            pk.z = f2bf(acc[r][c][2]);
            pk.w = f2bf(acc[r][c][3]);
            if (colb < H)
                *(ushort4*)(z + (size_t)grow * H + colb) = pk;
            else
                *(ushort4*)(yb + (size_t)grow * H + (colb - H)) = pk;
        }
    }
}

// ---------------- R18 gather + epilogue: 8-in-flight halves, 8 waves/SIMD ----------------

__global__ __launch_bounds__(256, 8) void k_aggnorm(
    const ushort* __restrict__ z, const ushort* __restrict__ yb,
    const int* __restrict__ ptr, const int* __restrict__ adj,
    const float* __restrict__ bl,
    ushort* __restrict__ hhi, ushort* __restrict__ hlo, int norm) {
    int gtid = blockIdx.x * blockDim.x + threadIdx.x;
    int node = gtid >> 4;                  // 16 lanes per node
    int sl   = threadIdx.x & 15;           // lane covers cols [sl*8, sl*8+8)
    if (node >= N_NODES) return;
    int beg = ptr[node], end = ptr[node + 1];
    int deg = end - beg;
    const ushort* zrow = z + sl * 8;
    float a[8];
#pragma unroll
    for (int k = 0; k < 8; ++k) a[k] = 0.f;

    for (int base = 0; base < deg; base += 16) {
        int m = deg - base;
        if (m > 16) m = 16;
        int idx = (sl < m) ? adj[beg + base + sl] : 0;
#pragma unroll
        for (int half = 0; half < 2; ++half) {
            int mh = m - half * 8;
            if (mh <= 0) continue;
            if (mh > 8) mh = 8;
            int hb = half * 8;
            short8 v[8];
#pragma unroll
            for (int jj = 0; jj < 8; ++jj) {
                int nj = __shfl(idx, hb + jj, 16);
                if (jj < mh) v[jj] = *(const short8*)(zrow + (size_t)nj * H);
            }
            if (mh == 8) {
#pragma unroll
                for (int k = 0; k < 8; ++k)
                    a[k] += ((bf2f((ushort)v[0][k]) + bf2f((ushort)v[1][k])) +
                             (bf2f((ushort)v[2][k]) + bf2f((ushort)v[3][k]))) +
                            ((bf2f((ushort)v[4][k]) + bf2f((ushort)v[5][k])) +
                             (bf2f((ushort)v[6][k]) + bf2f((ushort)v[7][k])));
            } else if (mh >= 4) {
#pragma unroll
                for (int k = 0; k < 8; ++k)
                    a[k] += (bf2f((ushort)v[0][k]) + bf2f((ushort)v[1][k])) +
                            (bf2f((ushort)v[2][k]) + bf2f((ushort)v[3][k]));
                if (mh > 4) {
#pragma unroll
                    for (int k = 0; k < 8; ++k) a[k] += bf2f((ushort)v[4][k]);
                }
                if (mh > 5) {
#pragma unroll
                    for (int k = 0; k < 8; ++k) a[k] += bf2f((ushort)v[5][k]);
                }
                if (mh > 6) {
#pragma unroll
                    for (int k = 0; k < 8; ++k) a[k] += bf2f((ushort)v[6][k]);
                }
            } else {
                if (mh > 0) {
#pragma unroll
                    for (int k = 0; k < 8; ++k) a[k] += bf2f((ushort)v[0][k]);
                }
                if (mh > 1) {
#pragma unroll
                    for (int k = 0; k < 8; ++k) a[k] += bf2f((ushort)v[1][k]);
                }
                if (mh > 2) {
#pragma unroll
                    for (int k = 0; k < 8; ++k) a[k] += bf2f((ushort)v[2][k]);
                }
            }
        }
    }

    float inv = 1.0f / (float)(deg > 1 ? deg : 1);
    short8 yv = *(const short8*)(yb + (size_t)node * H + sl * 8);
    float4 bva = *(const float4*)(bl + sl * 8);
    float4 bvb = *(const float4*)(bl + sl * 8 + 4);
    float vv[8];
    vv[0] = a[0] * inv + bva.x + bf2f((ushort)yv[0]);
    vv[1] = a[1] * inv + bva.y + bf2f((ushort)yv[1]);
    vv[2] = a[2] * inv + bva.z + bf2f((ushort)yv[2]);
    vv[3] = a[3] * inv + bva.w + bf2f((ushort)yv[3]);
    vv[4] = a[4] * inv + bvb.x + bf2f((ushort)yv[4]);
    vv[5] = a[5] * inv + bvb.y + bf2f((ushort)yv[5]);
    vv[6] = a[6] * inv + bvb.z + bf2f((ushort)yv[6]);
    vv[7] = a[7] * inv + bvb.w + bf2f((ushort)yv[7]);
    if (norm) {
        float ss = 0.f;
#pragma unroll
        for (int k = 0; k < 8; ++k) ss += vv[k] * vv[k];
#pragma unroll
        for (int mm = 1; mm < 16; mm <<= 1) ss += __shfl_xor(ss, mm, 16);
        float n2 = 1.0f / fmaxf(sqrtf(ss), 1e-12f);
#pragma unroll
        for (int k = 0; k < 8; ++k) vv[k] *= n2;
    }
    short8 ho, lo8;
#pragma unroll
    for (int k = 0; k < 8; ++k) {
        ushort hh = f2bf(vv[k]);
        ho[k]  = (short)hh;
        lo8[k] = (short)f2bf(vv[k] - bf2f(hh));
    }
    *(short8*)(hhi + (size_t)node * H + sl * 8) = ho;
    *(short8*)(hlo + (size_t)node * H + sl * 8) = lo8;
}

// ---------------- global add pool (batch sorted), h = hi + lo ----------------

constexpr int POOL_ROWS = 64;

__global__ void k_pool(const ushort* __restrict__ hhi, const ushort* __restrict__ hlo,
                       const int* __restrict__ batch, float* __restrict__ g) {
    int col = threadIdx.x;  // 0..127
    int r0 = blockIdx.x * POOL_ROWS;
    int r1 = r0 + POOL_ROWS;
    if (r1 > N_NODES) r1 = N_NODES;
    if (r0 >= N_NODES) return;
    float acc = 0.f;
    int cur = batch[r0];
    int r = r0;
    for (; r + 4 <= r1; r += 4) {
        float v0 = bf2f(hhi[(size_t)r * H + col])       + bf2f(hlo[(size_t)r * H + col]);
        float v1 = bf2f(hhi[(size_t)(r + 1) * H + col]) + bf2f(hlo[(size_t)(r + 1) * H + col]);
        float v2 = bf2f(hhi[(size_t)(r + 2) * H + col]) + bf2f(hlo[(size_t)(r + 2) * H + col]);
        float v3 = bf2f(hhi[(size_t)(r + 3) * H + col]) + bf2f(hlo[(size_t)(r + 3) * H + col]);
        int b3 = batch[r + 3];
        if (b3 == cur) {
            acc += (v0 + v1) + (v2 + v3);
        } else {
            int b0 = batch[r], b1 = batch[r + 1], b2 = batch[r + 2];
            if (b0 != cur) { atomicAdd(&g[cur * H + col], acc); acc = 0.f; cur = b0; }
            acc += v0;
            if (b1 != cur) { atomicAdd(&g[cur * H + col], acc); acc = 0.f; cur = b1; }
            acc += v1;
            if (b2 != cur) { atomicAdd(&g[cur * H + col], acc); acc = 0.f; cur = b2; }
            acc += v2;
            if (b3 != cur) { atomicAdd(&g[cur * H + col], acc); acc = 0.f; cur = b3; }
            acc += v3;
        }
    }
    for (; r < r1; ++r) {
        int b = batch[r];
        if (b != cur) { atomicAdd(&g[cur * H + col], acc); acc = 0.f; cur = b; }
        acc += bf2f(hhi[(size_t)r * H + col]) + bf2f(hlo[(size_t)r * H + col]);
    }
    atomicAdd(&g[cur * H + col], acc);
}

// ---------------- MLP head ----------------

__global__ void k_mlp(const float* __restrict__ g, const float* __restrict__ W0,
                      const float* __restrict__ b0, const float* __restrict__ W1,
                      const float* __restrict__ b1, const float* __restrict__ Wh,
                      const float* __restrict__ bh, float* __restrict__ out) {
    int gi = blockIdx.x;
    int t  = threadIdx.x;  // 0..127
    __shared__ float buf0[H];
    __shared__ float buf1[H];
    __shared__ float red[2];

    float acc = b0[t];
    for (int k = 0; k < H; ++k) acc += g[gi * H + k] * W0[k * H + t];
    buf0[t] = fmaxf(acc, 0.f);
    __syncthreads();

    acc = b1[t];
    for (int k = 0; k < H; ++k) acc += buf0[k] * W1[k * H + t];
    buf1[t] = fmaxf(acc, 0.f);
    __syncthreads();

    float p = buf1[t] * Wh[t];
    for (int m = 1; m < 64; m <<= 1) p += __shfl_xor(p, m, 64);
    if ((t & 63) == 0) red[t >> 6] = p;
    __syncthreads();
    if (t == 0) out[gi] = red[0] + red[1] + bh[0];
}

// ---------------- driver ----------------

extern "C" void kernel_launch(void* const* d_in, const int* in_sizes, int n_in,
                              void* d_out, int out_size, void* d_ws, size_t ws_size,
                              hipStream_t stream) {
    const float* x     = (const float*)d_in[0];
    const int*   eic   = (const int*)d_in[1];
    const int*   eid   = (const int*)d_in[2];
    const int*   eit   = (const int*)d_in[3];
    const int*   batch = (const int*)d_in[4];
    const float* cW[5][3];
    for (int c = 0; c < 5; ++c) {
        cW[c][0] = (const float*)d_in[5 + c * 3 + 0];  // Wl
        cW[c][1] = (const float*)d_in[5 + c * 3 + 1];  // bl
        cW[c][2] = (const float*)d_in[5 + c * 3 + 2];  // Wr
    }
    const float* l0_W = (const float*)d_in[20];
    const float* l0_b = (const float*)d_in[21];
    const float* l1_W = (const float*)d_in[22];
    const float* l1_b = (const float*)d_in[23];
    const float* hd_W = (const float*)d_in[24];
    const float* hd_b = (const float*)d_in[25];
    float* outp = (float*)d_out;

    const size_t NH = (size_t)N_NODES * H;
    ushort* Ahi = (ushort*)d_ws;
    ushort* Alo = Ahi + NH;
    ushort* zb  = Alo + NH;
    ushort* yb  = zb + NH;
    ushort* Bpk = yb + NH;                     // 5 convs x 2 planes x 32768
    float*  gbuf = (float*)(Bpk + 5 * 2 * 32768);
    int* gcnt = (int*)(gbuf + (size_t)NG * H);     // zeroed by k_prep
    int* rcnt = gcnt + NB;                         // zeroed by k_prep
    int* ptr_all = rcnt + NB;                      // N3+1 ints (persistent)
    int* adj_all = ptr_all + (N3 + 1);             // 3*NE ints (persistent)
    // CSR-build scratch inside zb+yb (dead until first gemm, stream-ordered):
    //   bucket[NB*CAP2 int2] (64B-aligned at zb)  = 22.88 MB < zb+yb (25.6MB)
    int2* bucket = (int2*)zb;

    dim3 b256(256);

    // merged prep: weight pre-scatter (blocks<640) + x split + zeroing
    k_prep<<<dim3(640 + (int)(NH / 1024)), b256, 0, stream>>>(
        x, Ahi, Alo, (int*)gbuf,
        cW[0][0], cW[0][2], cW[1][0], cW[1][2], cW[2][0], cW[2][2],
        cW[3][0], cW[3][2], cW[4][0], cW[4][2], Bpk);

    // CSR build: bucketize -> per-bucket (total-scan + ptr + scatter)
    k_bucketize<<<dim3(3 * BPS), b256, 0, stream>>>(eic, eid, eit, gcnt, rcnt, bucket);
    k_scatter2<<<dim3(NB), dim3(512), 0, stream>>>(bucket, gcnt, rcnt, ptr_all, adj_all);

    const int L_set[7]  = {1, 0, 0, 2, 1, 0, 0};
    const int L_conv[7] = {0, 1, 1, 2, 3, 4, 4};
    const int L_norm[7] = {1, 1, 1, 0, 1, 1, 1};

    dim3 gAgg((N_NODES * 16 + 255) / 256);   // 16 lanes/node -> 3125 blocks
    dim3 gGemm((N_NODES + 63) / 64);         // 782

    for (int L = 0; L < 7; ++L) {
        int s = L_set[L], c = L_conv[L];
        const ushort* Bh = Bpk + (size_t)c * 65536;
        const ushort* Bl = Bh + 32768;
        k_gemm_mfma<<<gGemm, b256, 0, stream>>>(Ahi, Alo, Bh, Bl, zb, yb);
        k_aggnorm<<<gAgg, b256, 0, stream>>>(zb, yb, ptr_all + s * N_NODES, adj_all,
                                             cW[c][1], Ahi, Alo, L_norm[L]);
    }

    k_pool<<<dim3((N_NODES + POOL_ROWS - 1) / POOL_ROWS), dim3(H), 0, stream>>>(
        Ahi, Alo, batch, gbuf);
    k_mlp<<<dim3(NG), dim3(H), 0, stream>>>(gbuf, l0_W, l0_b, l1_W, l1_b, hd_W, hd_b,
                                            outp);
}

// Round 10
// 472.294 us; speedup vs baseline: 1.1716x; 1.1021x over previous
//
#include <hip/hip_runtime.h>
#include <hip/hip_bf16.h>

// ValueNet: 7x SAGEConv(mean) + global_add_pool + MLP head.
// N=50000 nodes, E=600000 edges/set, H=128, G=64 graphs.
//
// out_i = mean_j(z_j) + bl + y_i,  z = h@Wl, y = h@Wr (linearity of mean).
// GEMM on MFMA bf16 with split precision (hi+lo planes, 3 MFMAs: hh+hl+lh).
// z,y stored bf16. h stored as hi/lo bf16 planes.
//
// R22: REVERT R21 epilogue (packed-store D^T regressed +11us). Re-do R20
//      fusion with its failure causes fixed: agg(L)+gemm(L+1) fused per
//      32-ROW block, 512 threads -> 1 node-chunk/thread (R18 shape, no
//      serial chunk loop), 1563 blocks (2x R20 balance), launch_bounds
//      (512,6) -> VGPR<=84, 3 blk/CU = 1536 thr/CU (~75% of R18 gather
//      concurrency, above the request-rate saturation point R18 showed).
//      h hi/lo stays in LDS (never HBM): saves 51MB + 1 boundary /layer.
//      z/y ping-pong pairs remove the read/write race. Bit-identical.
// R18: aggnorm 8-in-flight halves (final layer standalone).
// R17: k_prep = merged wsplit+split+zeroing.
// R14: gemm0 (from x) global_load_lds(16B) staging, XOR-swizzled source.
// CSR build (R12): LDS-staged bucket sort, NO per-key global atomics.
//
// Agg floor note (R13-R20): ~36-40us/layer invariant to instructions, L2
// residency, ILP, occupancy, fusion-bytes -> L2 random-line request-rate
// floor. Fusion targets the OTHER costs (h traffic, boundaries).

constexpr int N_NODES = 50000;
constexpr int NE      = 600000;
constexpr int H       = 128;
constexpr int NG      = 64;
constexpr int N3      = 3 * N_NODES;            // 150000

constexpr int NB   = (N3 + 1023) >> 10;          // 147 buckets (1024 keys each)
constexpr int EPB  = 2048;                       // edges per block (phase A)
constexpr int BPS  = (NE + EPB - 1) / EPB;       // 293 blocks per edge set
constexpr int CAP2 = 19456;                      // slots/bucket (exp ~15.4k padded; mult of 8)

typedef __attribute__((ext_vector_type(8))) short short8;
typedef __attribute__((ext_vector_type(4))) float f32x4;

__device__ __forceinline__ ushort f2bf(float f) {  // RNE float->bf16
    uint x = __float_as_uint(f);
    return (ushort)((x + 0x7FFFu + ((x >> 16) & 1u)) >> 16);
}
__device__ __forceinline__ float bf2f(ushort u) {
    return __uint_as_float(((uint)u) << 16);
}

// ---------------- Phase A: LDS-staged bucketize (padded, sentinel-filled) ----------------

__global__ __launch_bounds__(256) void k_bucketize(
    const int* __restrict__ e0, const int* __restrict__ e1,
    const int* __restrict__ e2, int* __restrict__ gcnt,
    int* __restrict__ rcnt, int2* __restrict__ bucket) {
    __shared__ int hist[NB];
    __shared__ int basearr[NB];
    __shared__ int cur[NB];
    __shared__ int gposs[NB];
    __shared__ int2 stage[EPB];
    __shared__ int dstoff[EPB];

    int t = threadIdx.x;
    int s = blockIdx.x / BPS;
    int w = blockIdx.x - s * BPS;
    const int* ep = (s == 0 ? e0 : (s == 1 ? e1 : e2));
    int eBase = w * EPB;
    int m = NE - eBase;
    if (m > EPB) m = EPB;

    for (int i = t; i < NB; i += 256) hist[i] = 0;
    __syncthreads();

    // pass 1: read edges into regs, LDS histogram
    int myk[EPB / 256], mys[EPB / 256];
#pragma unroll
    for (int k = 0; k < EPB / 256; ++k) {
        int i = t + 256 * k;
        if (i < m) {
            int d   = ep[NE + eBase + i];
            int src = ep[eBase + i];
            int key = s * N_NODES + d;
            myk[k] = key; mys[k] = src;
            atomicAdd(&hist[key >> 10], 1);
        } else {
            myk[k] = -1;
        }
    }
    __syncthreads();

    if (t == 0) {  // serial scan over 147 entries (cheap)
        int run = 0;
        for (int b = 0; b < NB; ++b) { basearr[b] = run; run += hist[b]; }
    }
    __syncthreads();

    if (t < NB) {  // padded reserve: ONE atomic per (block,bucket); runs 64B-aligned
        int h = hist[t];
        int p = (h + 7) & ~7;
        gposs[t] = p ? atomicAdd(&gcnt[t], p) : 0;
        if (h) atomicAdd(&rcnt[t], h);
        cur[t] = 0;
    }
    __syncthreads();

    // pass 2: scatter into LDS stage in bucket order; record dense dst offsets
#pragma unroll
    for (int k = 0; k < EPB / 256; ++k) {
        if (myk[k] >= 0) {
            int b  = myk[k] >> 10;
            int sl = atomicAdd(&cur[b], 1);
            int p  = basearr[b] + sl;
            stage[p]  = make_int2(myk[k], mys[k]);
            dstoff[p] = b * CAP2 + gposs[b] + sl;
        }
    }
    __syncthreads();

    // copyout: consecutive stage slots within a run -> consecutive global addrs
    for (int i = t; i < m; i += 256) bucket[dstoff[i]] = stage[i];
    // sentinel-fill the pad slots (<=7 per (block,bucket), same lines as runs)
    for (int i = t; i < NB * 8; i += 256) {
        int b = i >> 3, j = i & 7;
        int h = hist[b];
        int p = (h + 7) & ~7;
        if (h + j < p)
            bucket[(size_t)b * CAP2 + gposs[b] + h + j] = make_int2(-1, 0);
    }
}

// ---------------- Phase B: per-bucket hist + scan -> ptr slice + adj scatter ----------------

__global__ __launch_bounds__(512) void k_scatter2(const int2* __restrict__ bucket,
                                                  const int* __restrict__ gcnt,
                                                  const int* __restrict__ rcnt,
                                                  int* __restrict__ ptr,
                                                  int* __restrict__ adj) {
    int b = blockIdx.x;           // 0..NB-1
    int base = b << 10;
    int nk = N3 - base;
    if (nk > 1024) nk = 1024;
    __shared__ int lh[1024];
    __shared__ int lsum[512];
    __shared__ int lfill[1024];
    __shared__ int bb;
    int t = threadIdx.x;

    // exclusive prefix of real bucket totals -> bb (value at index b only)
    int rv = (t < NB) ? rcnt[t] : 0;
    lsum[t] = rv;
    __syncthreads();
    for (int off = 1; off < 512; off <<= 1) {
        int u = (t >= off) ? lsum[t - off] : 0;
        __syncthreads();
        if (t >= off) lsum[t] += u;
        __syncthreads();
    }
    if (t == b) bb = lsum[t] - rv;
    if (b == 0 && t == 0) ptr[N3] = 3 * NE;
    for (int i = t; i < 1024; i += 512) lh[i] = 0;
    __syncthreads();

    int c = gcnt[b];              // padded slot count actually used
    const int2* seg = bucket + (size_t)b * CAP2;
    for (int i = t; i < c; i += 512) {
        int k = seg[i].x;
        if (k >= 0) atomicAdd(&lh[k - base], 1);
    }
    __syncthreads();
    // exclusive 1024-scan: 2 seq per thread + 512 Hillis-Steele
    int v0 = lh[t * 2], v1 = lh[t * 2 + 1];
    int ts = v0 + v1;
    lsum[t] = ts;
    __syncthreads();
    for (int off = 1; off < 512; off <<= 1) {
        int u = (t >= off) ? lsum[t - off] : 0;
        __syncthreads();
        if (t >= off) lsum[t] += u;
        __syncthreads();
    }
    int ex = lsum[t] - ts + bb;
    int e0 = ex, e1 = ex + v0;
    if (t * 2     < nk) { ptr[base + t * 2]     = e0; lfill[t * 2]     = e0; }
    if (t * 2 + 1 < nk) { ptr[base + t * 2 + 1] = e1; lfill[t * 2 + 1] = e1; }
    __syncthreads();
    for (int i = t; i < c; i += 512) {
        int2 ed = seg[i];
        if (ed.x >= 0) {
            int pos = atomicAdd(&lfill[ed.x - base], 1);
            adj[pos] = ed.y;
        }
    }
}

// ---------------- R17: merged prep = weight pre-scatter + x split + zeroing ----------------

__global__ void k_prep(const float* __restrict__ x, ushort* __restrict__ hi,
                       ushort* __restrict__ lo, int* __restrict__ zmem,
                       const float* W0l, const float* W0r, const float* W1l,
                       const float* W1r, const float* W2l, const float* W2r,
                       const float* W3l, const float* W3r, const float* W4l,
                       const float* W4r, ushort* __restrict__ Bpk) {
    int bid = blockIdx.x;
    int t   = threadIdx.x;
    if (bid < 640) {
        int idx = bid * 256 + t;  // 0..5*32768-1
        if (idx >= 5 * 32768) return;
        int c = idx >> 15, r = idx & 32767;
        const float* Wl = (c == 0 ? W0l : c == 1 ? W1l : c == 2 ? W2l : c == 3 ? W3l : W4l);
        const float* Wr = (c == 0 ? W0r : c == 1 ? W1r : c == 2 ? W2r : c == 3 ? W3r : W4r);
        int n = r & 255, k = r >> 8;
        float w = (n < H) ? Wl[k * H + n] : Wr[k * H + (n - H)];
        int q = k >> 5, g = (k >> 3) & 3, j = k & 7;
        int off = ((q * 4 + g) * 256 + n) * 8 + j;
        ushort h = f2bf(w);
        ushort* bh = Bpk + (size_t)c * 65536;
        bh[off]         = h;
        bh[32768 + off] = f2bf(w - bf2f(h));
        return;
    }
    int tid = (bid - 640) * 256 + t;
    if (tid < NG * H + 2 * NB) zmem[tid] = 0;   // gbuf + gcnt + rcnt
    size_t i = (size_t)tid * 4;
    if (i >= (size_t)N_NODES * H) return;
    float4 v = *(const float4*)(x + i);
    ushort4 h, l;
    h.x = f2bf(v.x); l.x = f2bf(v.x - bf2f(h.x));
    h.y = f2bf(v.y); l.y = f2bf(v.y - bf2f(h.y));
    h.z = f2bf(v.z); l.z = f2bf(v.z - bf2f(h.z));
    h.w = f2bf(v.w); l.w = f2bf(v.w - bf2f(h.w));
    *(ushort4*)(hi + i) = h;
    *(ushort4*)(lo + i) = l;
}

// ---------------- MFMA GEMM (layer 1, A = x planes): R14/R18 version ----------------

__global__ __launch_bounds__(256) void k_gemm_mfma(
    const ushort* __restrict__ Ahi, const ushort* __restrict__ Alo,
    const ushort* __restrict__ Bh, const ushort* __restrict__ Bl,
    ushort* __restrict__ z, ushort* __restrict__ yb) {
    __shared__ ushort AshF[2 * 64 * 128];   // 32 KB
    int t = threadIdx.x;
    int rowBase = blockIdx.x * 64;
    {
        int wslot = t & ~63;                 // wave-uniform slot base
        int lane  = t & 63;
#pragma unroll
        for (int i = 0; i < 8; ++i) {
            int sbase = i * 256 + wslot;     // wave's first slot this round
            int S     = sbase + lane;        // this lane's slot
            int plane = S >> 10;
            int row   = (S >> 4) & 63;
            int pc    = S & 15;
            int grow  = rowBase + row;
            if (grow > N_NODES - 1) grow = N_NODES - 1;
            const ushort* Ap  = plane ? Alo : Ahi;
            const ushort* src = Ap + (size_t)grow * H + ((pc ^ (row & 15)) << 3);
            ushort* ldst = AshF + (size_t)sbase * 8;   // wave-uniform; HW adds lane*16B
            __builtin_amdgcn_global_load_lds(
                (const __attribute__((address_space(1))) void*)src,
                (__attribute__((address_space(3))) void*)ldst, 16, 0, 0);
        }
    }
    __syncthreads();

    int wave = t >> 6, lane = t & 63;
    int m16 = lane & 15, q4 = lane >> 4;
    int n0 = wave * 64;

    f32x4 acc[4][4];
#pragma unroll
    for (int r = 0; r < 4; ++r)
#pragma unroll
        for (int c = 0; c < 4; ++c) {
            acc[r][c][0] = 0.f; acc[r][c][1] = 0.f;
            acc[r][c][2] = 0.f; acc[r][c][3] = 0.f;
        }

    for (int q = 0; q < 4; ++q) {
        short8 bh_[4], bl_[4], ah_[4], al_[4];
#pragma unroll
        for (int c = 0; c < 4; ++c) {
            int boff = ((q * 4 + q4) * 256 + n0 + c * 16 + m16) * 8;
            bh_[c] = *(const short8*)(Bh + boff);
            bl_[c] = *(const short8*)(Bl + boff);
        }
#pragma unroll
        for (int r = 0; r < 4; ++r) {
            int roff = ((r * 16 + m16) << 7) + (((q * 4 + q4) ^ m16) << 3);
            ah_[r] = *(const short8*)&AshF[roff];
            al_[r] = *(const short8*)&AshF[8192 + roff];
        }
#pragma unroll
        for (int r = 0; r < 4; ++r)
#pragma unroll
            for (int c = 0; c < 4; ++c) {
                acc[r][c] = __builtin_amdgcn_mfma_f32_16x16x32_bf16(
                    ah_[r], bh_[c], acc[r][c], 0, 0, 0);
                acc[r][c] = __builtin_amdgcn_mfma_f32_16x16x32_bf16(
                    ah_[r], bl_[c], acc[r][c], 0, 0, 0);
                acc[r][c] = __builtin_amdgcn_mfma_f32_16x16x32_bf16(
                    al_[r], bh_[c], acc[r][c], 0, 0, 0);
            }
    }

    // C/D layout: col=lane&15, row=(lane>>4)*4+reg (m89-verified)
#pragma unroll
    for (int r = 0; r < 4; ++r)
#pragma unroll
        for (int c = 0; c < 4; ++c) {
            int col = n0 + c * 16 + m16;
            ushort* op = (col < H) ? (z + col) : (yb + (col - H));
#pragma unroll
            for (int j = 0; j < 4; ++j) {
                int gr = rowBase + r * 16 + q4 * 4 + j;
                if (gr < N_NODES) op[(size_t)gr * H] = f2bf(acc[r][c][j]);
            }
        }
}

// ---------------- R22: fused agg(L)+gemm(L+1), 32 rows, 512 threads ----------------
// agg: 1 node-chunk/thread (R18 shape, 16 lanes/node, 32 nodes/block);
// h hi/lo -> LDS only. gemm: 8 waves, wave w = (wr = w&1 row-tile, wc =
// w>>1 col-group of 64); fragments loaded per col-tile (low VGPR).

__global__ __launch_bounds__(512, 6) void k_fused2(
    const ushort* __restrict__ zin, const ushort* __restrict__ yin,
    ushort* __restrict__ zout, ushort* __restrict__ yout,
    const int* __restrict__ ptr, const int* __restrict__ adj,
    const float* __restrict__ bl,
    const ushort* __restrict__ Bh, const ushort* __restrict__ Blw,
    int norm) {
    __shared__ ushort Ash[2][32][136];   // 17.4 KB
    int t = threadIdx.x;
    int rowBase = blockIdx.x * 32;
    int sl  = t & 15;
    int row = t >> 4;                    // 0..31

    // ---- AGG phase (layer L): R18 body, one node per 16-lane group ----
    {
        int node = rowBase + row;
        if (node > N_NODES - 1) node = N_NODES - 1;   // clamp (dup; C-write guarded)
        int beg = ptr[node], end = ptr[node + 1];
        int deg = end - beg;
        const ushort* zrow = zin + sl * 8;
        float a[8];
#pragma unroll
        for (int k = 0; k < 8; ++k) a[k] = 0.f;

        for (int base = 0; base < deg; base += 16) {
            int m = deg - base;
            if (m > 16) m = 16;
            int idx = (sl < m) ? adj[beg + base + sl] : 0;
#pragma unroll
            for (int half = 0; half < 2; ++half) {
                int mh = m - half * 8;
                if (mh <= 0) continue;
                if (mh > 8) mh = 8;
                int hb = half * 8;
                short8 v[8];
#pragma unroll
                for (int jj = 0; jj < 8; ++jj) {
                    int nj = __shfl(idx, hb + jj, 16);
                    if (jj < mh) v[jj] = *(const short8*)(zrow + (size_t)nj * H);
                }
                if (mh == 8) {
#pragma unroll
                    for (int k = 0; k < 8; ++k)
                        a[k] += ((bf2f((ushort)v[0][k]) + bf2f((ushort)v[1][k])) +
                                 (bf2f((ushort)v[2][k]) + bf2f((ushort)v[3][k]))) +
                                ((bf2f((ushort)v[4][k]) + bf2f((ushort)v[5][k])) +
                                 (bf2f((ushort)v[6][k]) + bf2f((ushort)v[7][k])));
                } else if (mh >= 4) {
#pragma unroll
                    for (int k = 0; k < 8; ++k)
                        a[k] += (bf2f((ushort)v[0][k]) + bf2f((ushort)v[1][k])) +
                                (bf2f((ushort)v[2][k]) + bf2f((ushort)v[3][k]));
                    if (mh > 4) {
#pragma unroll
                        for (int k = 0; k < 8; ++k) a[k] += bf2f((ushort)v[4][k]);
                    }
                    if (mh > 5) {
#pragma unroll
                        for (int k = 0; k < 8; ++k) a[k] += bf2f((ushort)v[5][k]);
                    }
                    if (mh > 6) {
#pragma unroll
                        for (int k = 0; k < 8; ++k) a[k] += bf2f((ushort)v[6][k]);
                    }
                } else {
                    if (mh > 0) {
#pragma unroll
                        for (int k = 0; k < 8; ++k) a[k] += bf2f((ushort)v[0][k]);
                    }
                    if (mh > 1) {
#pragma unroll
                        for (int k = 0; k < 8; ++k) a[k] += bf2f((ushort)v[1][k]);
                    }
                    if (mh > 2) {
#pragma unroll
                        for (int k = 0; k < 8; ++k) a[k] += bf2f((ushort)v[2][k]);
                    }
                }
            }
        }

        float inv = 1.0f / (float)(deg > 1 ? deg : 1);
        short8 yv = *(const short8*)(yin + (size_t)node * H + sl * 8);
        float4 bva = *(const float4*)(bl + sl * 8);
        float4 bvb = *(const float4*)(bl + sl * 8 + 4);
        float vv[8];
        vv[0] = a[0] * inv + bva.x + bf2f((ushort)yv[0]);
        vv[1] = a[1] * inv + bva.y + bf2f((ushort)yv[1]);
        vv[2] = a[2] * inv + bva.z + bf2f((ushort)yv[2]);
        vv[3] = a[3] * inv + bva.w + bf2f((ushort)yv[3]);
        vv[4] = a[4] * inv + bvb.x + bf2f((ushort)yv[4]);
        vv[5] = a[5] * inv + bvb.y + bf2f((ushort)yv[5]);
        vv[6] = a[6] * inv + bvb.z + bf2f((ushort)yv[6]);
        vv[7] = a[7] * inv + bvb.w + bf2f((ushort)yv[7]);
        if (norm) {
            float ss = 0.f;
#pragma unroll
            for (int k = 0; k < 8; ++k) ss += vv[k] * vv[k];
#pragma unroll
            for (int mm = 1; mm < 16; mm <<= 1) ss += __shfl_xor(ss, mm, 16);
            float n2 = 1.0f / fmaxf(sqrtf(ss), 1e-12f);
#pragma unroll
            for (int k = 0; k < 8; ++k) vv[k] *= n2;
        }
        short8 ho, lo8;
#pragma unroll
        for (int k = 0; k < 8; ++k) {
            ushort hh = f2bf(vv[k]);
            ho[k]  = (short)hh;
            lo8[k] = (short)f2bf(vv[k] - bf2f(hh));
        }
        *(short8*)&Ash[0][row][sl * 8] = ho;     // h stays in LDS
        *(short8*)&Ash[1][row][sl * 8] = lo8;
    }
    __syncthreads();

    // ---- GEMM phase (layer L+1): 8 waves over 32x256 output ----
    int wave = t >> 6, lane = t & 63;
    int m16 = lane & 15, q4 = lane >> 4;
    int wr = wave & 1;                   // row tile (16 rows)
    int n0 = (wave >> 1) * 64;           // col group

    f32x4 acc[4];
#pragma unroll
    for (int c = 0; c < 4; ++c) {
        acc[c][0] = 0.f; acc[c][1] = 0.f; acc[c][2] = 0.f; acc[c][3] = 0.f;
    }

    for (int q = 0; q < 4; ++q) {
        short8 ah_ = *(const short8*)&Ash[0][wr * 16 + m16][q * 32 + q4 * 8];
        short8 al_ = *(const short8*)&Ash[1][wr * 16 + m16][q * 32 + q4 * 8];
#pragma unroll
        for (int c = 0; c < 4; ++c) {
            int boff = ((q * 4 + q4) * 256 + n0 + c * 16 + m16) * 8;
            short8 bh_ = *(const short8*)(Bh + boff);
            short8 bl_ = *(const short8*)(Blw + boff);
            acc[c] = __builtin_amdgcn_mfma_f32_16x16x32_bf16(ah_, bh_, acc[c], 0, 0, 0);
            acc[c] = __builtin_amdgcn_mfma_f32_16x16x32_bf16(ah_, bl_, acc[c], 0, 0, 0);
            acc[c] = __builtin_amdgcn_mfma_f32_16x16x32_bf16(al_, bh_, acc[c], 0, 0, 0);
        }
    }

    // C/D layout: col=lane&15, row=(lane>>4)*4+reg (m89-verified)
#pragma unroll
    for (int c = 0; c < 4; ++c) {
        int col = n0 + c * 16 + m16;
        ushort* op = (col < H) ? (zout + col) : (yout + (col - H));
#pragma unroll
        for (int j = 0; j < 4; ++j) {
            int gr = rowBase + wr * 16 + q4 * 4 + j;
            if (gr < N_NODES) op[(size_t)gr * H] = f2bf(acc[c][j]);
        }
    }
}

// ---------------- R18 gather + epilogue (final layer, writes h to global) ----------------

__global__ __launch_bounds__(256, 8) void k_aggnorm(
    const ushort* __restrict__ z, const ushort* __restrict__ yb,
    const int* __restrict__ ptr, const int* __restrict__ adj,
    const float* __restrict__ bl,
    ushort* __restrict__ hhi, ushort* __restrict__ hlo, int norm) {
    int gtid = blockIdx.x * blockDim.x + threadIdx.x;
    int node = gtid >> 4;                  // 16 lanes per node
    int sl   = threadIdx.x & 15;           // lane covers cols [sl*8, sl*8+8)
    if (node >= N_NODES) return;
    int beg = ptr[node], end = ptr[node + 1];
    int deg = end - beg;
    const ushort* zrow = z + sl * 8;
    float a[8];
#pragma unroll
    for (int k = 0; k < 8; ++k) a[k] = 0.f;

    for (int base = 0; base < deg; base += 16) {
        int m = deg - base;
        if (m > 16) m = 16;
        int idx = (sl < m) ? adj[beg + base + sl] : 0;
#pragma unroll
        for (int half = 0; half < 2; ++half) {
            int mh = m - half * 8;
            if (mh <= 0) continue;
            if (mh > 8) mh = 8;
            int hb = half * 8;
            short8 v[8];
#pragma unroll
            for (int jj = 0; jj < 8; ++jj) {
                int nj = __shfl(idx, hb + jj, 16);
                if (jj < mh) v[jj] = *(const short8*)(zrow + (size_t)nj * H);
            }
            if (mh == 8) {
#pragma unroll
                for (int k = 0; k < 8; ++k)
                    a[k] += ((bf2f((ushort)v[0][k]) + bf2f((ushort)v[1][k])) +
                             (bf2f((ushort)v[2][k]) + bf2f((ushort)v[3][k]))) +
                            ((bf2f((ushort)v[4][k]) + bf2f((ushort)v[5][k])) +
                             (bf2f((ushort)v[6][k]) + bf2f((ushort)v[7][k])));
            } else if (mh >= 4) {
#pragma unroll
                for (int k = 0; k < 8; ++k)
                    a[k] += (bf2f((ushort)v[0][k]) + bf2f((ushort)v[1][k])) +
                            (bf2f((ushort)v[2][k]) + bf2f((ushort)v[3][k]));
                if (mh > 4) {
#pragma unroll
                    for (int k = 0; k < 8; ++k) a[k] += bf2f((ushort)v[4][k]);
                }
                if (mh > 5) {
#pragma unroll
                    for (int k = 0; k < 8; ++k) a[k] += bf2f((ushort)v[5][k]);
                }
                if (mh > 6) {
#pragma unroll
                    for (int k = 0; k < 8; ++k) a[k] += bf2f((ushort)v[6][k]);
                }
            } else {
                if (mh > 0) {
#pragma unroll
                    for (int k = 0; k < 8; ++k) a[k] += bf2f((ushort)v[0][k]);
                }
                if (mh > 1) {
#pragma unroll
                    for (int k = 0; k < 8; ++k) a[k] += bf2f((ushort)v[1][k]);
                }
                if (mh > 2) {
#pragma unroll
                    for (int k = 0; k < 8; ++k) a[k] += bf2f((ushort)v[2][k]);
                }
            }
        }
    }

    float inv = 1.0f / (float)(deg > 1 ? deg : 1);
    short8 yv = *(const short8*)(yb + (size_t)node * H + sl * 8);
    float4 bva = *(const float4*)(bl + sl * 8);
    float4 bvb = *(const float4*)(bl + sl * 8 + 4);
    float vv[8];
    vv[0] = a[0] * inv + bva.x + bf2f((ushort)yv[0]);
    vv[1] = a[1] * inv + bva.y + bf2f((ushort)yv[1]);
    vv[2] = a[2] * inv + bva.z + bf2f((ushort)yv[2]);
    vv[3] = a[3] * inv + bva.w + bf2f((ushort)yv[3]);
    vv[4] = a[4] * inv + bvb.x + bf2f((ushort)yv[4]);
    vv[5] = a[5] * inv + bvb.y + bf2f((ushort)yv[5]);
    vv[6] = a[6] * inv + bvb.z + bf2f((ushort)yv[6]);
    vv[7] = a[7] * inv + bvb.w + bf2f((ushort)yv[7]);
    if (norm) {
        float ss = 0.f;
#pragma unroll
        for (int k = 0; k < 8; ++k) ss += vv[k] * vv[k];
#pragma unroll
        for (int mm = 1; mm < 16; mm <<= 1) ss += __shfl_xor(ss, mm, 16);
        float n2 = 1.0f / fmaxf(sqrtf(ss), 1e-12f);
#pragma unroll
        for (int k = 0; k < 8; ++k) vv[k] *= n2;
    }
    short8 ho, lo8;
#pragma unroll
    for (int k = 0; k < 8; ++k) {
        ushort hh = f2bf(vv[k]);
        ho[k]  = (short)hh;
        lo8[k] = (short)f2bf(vv[k] - bf2f(hh));
    }
    *(short8*)(hhi + (size_t)node * H + sl * 8) = ho;
    *(short8*)(hlo + (size_t)node * H + sl * 8) = lo8;
}

// ---------------- global add pool (batch sorted), h = hi + lo ----------------

constexpr int POOL_ROWS = 64;

__global__ void k_pool(const ushort* __restrict__ hhi, const ushort* __restrict__ hlo,
                       const int* __restrict__ batch, float* __restrict__ g) {
    int col = threadIdx.x;  // 0..127
    int r0 = blockIdx.x * POOL_ROWS;
    int r1 = r0 + POOL_ROWS;
    if (r1 > N_NODES) r1 = N_NODES;
    if (r0 >= N_NODES) return;
    float acc = 0.f;
    int cur = batch[r0];
    int r = r0;
    for (; r + 4 <= r1; r += 4) {
        float v0 = bf2f(hhi[(size_t)r * H + col])       + bf2f(hlo[(size_t)r * H + col]);
        float v1 = bf2f(hhi[(size_t)(r + 1) * H + col]) + bf2f(hlo[(size_t)(r + 1) * H + col]);
        float v2 = bf2f(hhi[(size_t)(r + 2) * H + col]) + bf2f(hlo[(size_t)(r + 2) * H + col]);
        float v3 = bf2f(hhi[(size_t)(r + 3) * H + col]) + bf2f(hlo[(size_t)(r + 3) * H + col]);
        int b3 = batch[r + 3];
        if (b3 == cur) {
            acc += (v0 + v1) + (v2 + v3);
        } else {
            int b0 = batch[r], b1 = batch[r + 1], b2 = batch[r + 2];
            if (b0 != cur) { atomicAdd(&g[cur * H + col], acc); acc = 0.f; cur = b0; }
            acc += v0;
            if (b1 != cur) { atomicAdd(&g[cur * H + col], acc); acc = 0.f; cur = b1; }
            acc += v1;
            if (b2 != cur) { atomicAdd(&g[cur * H + col], acc); acc = 0.f; cur = b2; }
            acc += v2;
            if (b3 != cur) { atomicAdd(&g[cur * H + col], acc); acc = 0.f; cur = b3; }
            acc += v3;
        }
    }
    for (; r < r1; ++r) {
        int b = batch[r];
        if (b != cur) { atomicAdd(&g[cur * H + col], acc); acc = 0.f; cur = b; }
        acc += bf2f(hhi[(size_t)r * H + col]) + bf2f(hlo[(size_t)r * H + col]);
    }
    atomicAdd(&g[cur * H + col], acc);
}

// ---------------- MLP head ----------------

__global__ void k_mlp(const float* __restrict__ g, const float* __restrict__ W0,
                      const float* __restrict__ b0, const float* __restrict__ W1,
                      const float* __restrict__ b1, const float* __restrict__ Wh,
                      const float* __restrict__ bh, float* __restrict__ out) {
    int gi = blockIdx.x;
    int t  = threadIdx.x;  // 0..127
    __shared__ float buf0[H];
    __shared__ float buf1[H];
    __shared__ float red[2];

    float acc = b0[t];
    for (int k = 0; k < H; ++k) acc += g[gi * H + k] * W0[k * H + t];
    buf0[t] = fmaxf(acc, 0.f);
    __syncthreads();

    acc = b1[t];
    for (int k = 0; k < H; ++k) acc += buf0[k] * W1[k * H + t];
    buf1[t] = fmaxf(acc, 0.f);
    __syncthreads();

    float p = buf1[t] * Wh[t];
    for (int m = 1; m < 64; m <<= 1) p += __shfl_xor(p, m, 64);
    if ((t & 63) == 0) red[t >> 6] = p;
    __syncthreads();
    if (t == 0) out[gi] = red[0] + red[1] + bh[0];
}

// ---------------- driver ----------------

extern "C" void kernel_launch(void* const* d_in, const int* in_sizes, int n_in,
                              void* d_out, int out_size, void* d_ws, size_t ws_size,
                              hipStream_t stream) {
    const float* x     = (const float*)d_in[0];
    const int*   eic   = (const int*)d_in[1];
    const int*   eid   = (const int*)d_in[2];
    const int*   eit   = (const int*)d_in[3];
    const int*   batch = (const int*)d_in[4];
    const float* cW[5][3];
    for (int c = 0; c < 5; ++c) {
        cW[c][0] = (const float*)d_in[5 + c * 3 + 0];  // Wl
        cW[c][1] = (const float*)d_in[5 + c * 3 + 1];  // bl
        cW[c][2] = (const float*)d_in[5 + c * 3 + 2];  // Wr
    }
    const float* l0_W = (const float*)d_in[20];
    const float* l0_b = (const float*)d_in[21];
    const float* l1_W = (const float*)d_in[22];
    const float* l1_b = (const float*)d_in[23];
    const float* hd_W = (const float*)d_in[24];
    const float* hd_b = (const float*)d_in[25];
    float* outp = (float*)d_out;

    const size_t NH = (size_t)N_NODES * H;
    ushort* Ahi = (ushort*)d_ws;
    ushort* Alo = Ahi + NH;
    ushort* zb0 = Alo + NH;                    // ping
    ushort* yb0 = zb0 + NH;
    ushort* zb1 = yb0 + NH;                    // pong
    ushort* yb1 = zb1 + NH;
    ushort* Bpk = yb1 + NH;                    // 5 convs x 2 planes x 32768
    float*  gbuf = (float*)(Bpk + 5 * 2 * 32768);
    int* gcnt = (int*)(gbuf + (size_t)NG * H);     // zeroed by k_prep
    int* rcnt = gcnt + NB;                         // zeroed by k_prep
    int* ptr_all = rcnt + NB;                      // N3+1 ints (persistent)
    int* adj_all = ptr_all + (N3 + 1);             // 3*NE ints (persistent)
    // CSR-build scratch inside zb0+yb0 (dead until gemm0, stream-ordered):
    //   bucket[NB*CAP2 int2] (64B-aligned at zb0) = 22.88 MB < 25.6MB
    int2* bucket = (int2*)zb0;

    dim3 b256(256);

    // merged prep: weight pre-scatter (blocks<640) + x split + zeroing
    k_prep<<<dim3(640 + (int)(NH / 1024)), b256, 0, stream>>>(
        x, Ahi, Alo, (int*)gbuf,
        cW[0][0], cW[0][2], cW[1][0], cW[1][2], cW[2][0], cW[2][2],
        cW[3][0], cW[3][2], cW[4][0], cW[4][2], Bpk);

    // CSR build: bucketize -> per-bucket (total-scan + ptr + scatter)
    k_bucketize<<<dim3(3 * BPS), b256, 0, stream>>>(eic, eid, eit, gcnt, rcnt, bucket);
    k_scatter2<<<dim3(NB), dim3(512), 0, stream>>>(bucket, gcnt, rcnt, ptr_all, adj_all);

    const int L_set[7]  = {1, 0, 0, 2, 1, 0, 0};
    const int L_conv[7] = {0, 1, 1, 2, 3, 4, 4};
    const int L_norm[7] = {1, 1, 1, 0, 1, 1, 1};

    dim3 gGemm((N_NODES + 63) / 64);         // 782
    dim3 gFused((N_NODES + 31) / 32);        // 1563
    dim3 gAgg((N_NODES * 16 + 255) / 256);   // 3125 (final layer only)

    // layer 1 GEMM from x planes -> pair0
    k_gemm_mfma<<<gGemm, b256, 0, stream>>>(Ahi, Alo, Bpk + (size_t)L_conv[0] * 65536,
                                            Bpk + (size_t)L_conv[0] * 65536 + 32768,
                                            zb0, yb0);

    // fused agg(L)+gemm(L+1), L=0..5, ping-pong z/y pairs
    for (int L = 0; L < 6; ++L) {
        ushort* zi = (L & 1) ? zb1 : zb0;
        ushort* yi = (L & 1) ? yb1 : yb0;
        ushort* zo = (L & 1) ? zb0 : zb1;
        ushort* yo = (L & 1) ? yb0 : yb1;
        const ushort* Bh = Bpk + (size_t)L_conv[L + 1] * 65536;
        const ushort* Bl = Bh + 32768;
        k_fused2<<<gFused, dim3(512), 0, stream>>>(zi, yi, zo, yo,
                                                   ptr_all + L_set[L] * N_NODES,
                                                   adj_all, cW[L_conv[L]][1], Bh, Bl,
                                                   L_norm[L]);
    }

    // final agg (L=6) reads pair0 (L=6 even), writes h hi/lo for pool
    k_aggnorm<<<gAgg, b256, 0, stream>>>(zb0, yb0, ptr_all + L_set[6] * N_NODES,
                                         adj_all, cW[L_conv[6]][1], Ahi, Alo,
                                         L_norm[6]);

    k_pool<<<dim3((N_NODES + POOL_ROWS - 1) / POOL_ROWS), dim3(H), 0, stream>>>(
        Ahi, Alo, batch, gbuf);
    k_mlp<<<dim3(NG), dim3(H), 0, stream>>>(gbuf, l0_W, l0_b, l1_W, l1_b, hd_W, hd_b,
                                            outp);
}

// Round 11
// 471.716 us; speedup vs baseline: 1.1730x; 1.0012x over previous
//
#include <hip/hip_runtime.h>
#include <hip/hip_bf16.h>

// ValueNet: 7x SAGEConv(mean) + global_add_pool + MLP head.
// N=50000 nodes, E=600000 edges/set, H=128, G=64 graphs.
//
// out_i = mean_j(z_j) + bl + y_i,  z = h@Wl, y = h@Wr (linearity of mean).
// GEMM on MFMA bf16 with split precision (hi+lo planes, 3 MFMAs: hh+hl+lh).
// z,y stored bf16.
//
// R23: (a) k_gemm0 reads x f32 DIRECTLY, converts to hi/lo bf16 in the
//      R13 [64][136] LDS tile in-kernel (same f2bf split; bit-identical)
//      -> kills prep's 25.6MB Ahi/Alo write + gemm0's 25.6MB re-read.
//      k_prep = weights + zeroing only (674 blocks).
//      (b) k_aggpool fuses final agg(L=6)+norm with global_add_pool:
//      vv accumulated f32 into per-graph LDS slots (batch sorted; 16-node
//      block spans ~1-2 graphs; gl>=16 falls back to global atomics),
//      then ~2x128 global atomicAdds/block. Kills 51.2MB h round trip,
//      k_pool, and a boundary.
// R22: fused agg(L)+gemm(L+1), 32 rows/512 thr, launch_bounds(512,6);
//      z/y ping-pong. 42.4us/dispatch measured, occupancy 44%.
// R18: agg 8-in-flight halves (v[8]) everywhere.
// CSR build (R12): LDS-staged bucket sort, NO per-key global atomics.
//
// Agg floor note (R13-R20): ~36-40us/layer invariant to instructions, L2
// residency, ILP, occupancy, fusion-bytes -> L2 random-line request-rate
// floor. Do not re-attack without a new mechanism.

constexpr int N_NODES = 50000;
constexpr int NE      = 600000;
constexpr int H       = 128;
constexpr int NG      = 64;
constexpr int N3      = 3 * N_NODES;            // 150000

constexpr int NB   = (N3 + 1023) >> 10;          // 147 buckets (1024 keys each)
constexpr int EPB  = 2048;                       // edges per block (phase A)
constexpr int BPS  = (NE + EPB - 1) / EPB;       // 293 blocks per edge set
constexpr int CAP2 = 19456;                      // slots/bucket (exp ~15.4k padded; mult of 8)

typedef __attribute__((ext_vector_type(8))) short short8;
typedef __attribute__((ext_vector_type(4))) float f32x4;

__device__ __forceinline__ ushort f2bf(float f) {  // RNE float->bf16
    uint x = __float_as_uint(f);
    return (ushort)((x + 0x7FFFu + ((x >> 16) & 1u)) >> 16);
}
__device__ __forceinline__ float bf2f(ushort u) {
    return __uint_as_float(((uint)u) << 16);
}

// ---------------- Phase A: LDS-staged bucketize (padded, sentinel-filled) ----------------

__global__ __launch_bounds__(256) void k_bucketize(
    const int* __restrict__ e0, const int* __restrict__ e1,
    const int* __restrict__ e2, int* __restrict__ gcnt,
    int* __restrict__ rcnt, int2* __restrict__ bucket) {
    __shared__ int hist[NB];
    __shared__ int basearr[NB];
    __shared__ int cur[NB];
    __shared__ int gposs[NB];
    __shared__ int2 stage[EPB];
    __shared__ int dstoff[EPB];

    int t = threadIdx.x;
    int s = blockIdx.x / BPS;
    int w = blockIdx.x - s * BPS;
    const int* ep = (s == 0 ? e0 : (s == 1 ? e1 : e2));
    int eBase = w * EPB;
    int m = NE - eBase;
    if (m > EPB) m = EPB;

    for (int i = t; i < NB; i += 256) hist[i] = 0;
    __syncthreads();

    // pass 1: read edges into regs, LDS histogram
    int myk[EPB / 256], mys[EPB / 256];
#pragma unroll
    for (int k = 0; k < EPB / 256; ++k) {
        int i = t + 256 * k;
        if (i < m) {
            int d   = ep[NE + eBase + i];
            int src = ep[eBase + i];
            int key = s * N_NODES + d;
            myk[k] = key; mys[k] = src;
            atomicAdd(&hist[key >> 10], 1);
        } else {
            myk[k] = -1;
        }
    }
    __syncthreads();

    if (t == 0) {  // serial scan over 147 entries (cheap)
        int run = 0;
        for (int b = 0; b < NB; ++b) { basearr[b] = run; run += hist[b]; }
    }
    __syncthreads();

    if (t < NB) {  // padded reserve: ONE atomic per (block,bucket); runs 64B-aligned
        int h = hist[t];
        int p = (h + 7) & ~7;
        gposs[t] = p ? atomicAdd(&gcnt[t], p) : 0;
        if (h) atomicAdd(&rcnt[t], h);
        cur[t] = 0;
    }
    __syncthreads();

    // pass 2: scatter into LDS stage in bucket order; record dense dst offsets
#pragma unroll
    for (int k = 0; k < EPB / 256; ++k) {
        if (myk[k] >= 0) {
            int b  = myk[k] >> 10;
            int sl = atomicAdd(&cur[b], 1);
            int p  = basearr[b] + sl;
            stage[p]  = make_int2(myk[k], mys[k]);
            dstoff[p] = b * CAP2 + gposs[b] + sl;
        }
    }
    __syncthreads();

    // copyout: consecutive stage slots within a run -> consecutive global addrs
    for (int i = t; i < m; i += 256) bucket[dstoff[i]] = stage[i];
    // sentinel-fill the pad slots (<=7 per (block,bucket), same lines as runs)
    for (int i = t; i < NB * 8; i += 256) {
        int b = i >> 3, j = i & 7;
        int h = hist[b];
        int p = (h + 7) & ~7;
        if (h + j < p)
            bucket[(size_t)b * CAP2 + gposs[b] + h + j] = make_int2(-1, 0);
    }
}

// ---------------- Phase B: per-bucket hist + scan -> ptr slice + adj scatter ----------------

__global__ __launch_bounds__(512) void k_scatter2(const int2* __restrict__ bucket,
                                                  const int* __restrict__ gcnt,
                                                  const int* __restrict__ rcnt,
                                                  int* __restrict__ ptr,
                                                  int* __restrict__ adj) {
    int b = blockIdx.x;           // 0..NB-1
    int base = b << 10;
    int nk = N3 - base;
    if (nk > 1024) nk = 1024;
    __shared__ int lh[1024];
    __shared__ int lsum[512];
    __shared__ int lfill[1024];
    __shared__ int bb;
    int t = threadIdx.x;

    // exclusive prefix of real bucket totals -> bb (value at index b only)
    int rv = (t < NB) ? rcnt[t] : 0;
    lsum[t] = rv;
    __syncthreads();
    for (int off = 1; off < 512; off <<= 1) {
        int u = (t >= off) ? lsum[t - off] : 0;
        __syncthreads();
        if (t >= off) lsum[t] += u;
        __syncthreads();
    }
    if (t == b) bb = lsum[t] - rv;
    if (b == 0 && t == 0) ptr[N3] = 3 * NE;
    for (int i = t; i < 1024; i += 512) lh[i] = 0;
    __syncthreads();

    int c = gcnt[b];              // padded slot count actually used
    const int2* seg = bucket + (size_t)b * CAP2;
    for (int i = t; i < c; i += 512) {
        int k = seg[i].x;
        if (k >= 0) atomicAdd(&lh[k - base], 1);
    }
    __syncthreads();
    // exclusive 1024-scan: 2 seq per thread + 512 Hillis-Steele
    int v0 = lh[t * 2], v1 = lh[t * 2 + 1];
    int ts = v0 + v1;
    lsum[t] = ts;
    __syncthreads();
    for (int off = 1; off < 512; off <<= 1) {
        int u = (t >= off) ? lsum[t - off] : 0;
        __syncthreads();
        if (t >= off) lsum[t] += u;
        __syncthreads();
    }
    int ex = lsum[t] - ts + bb;
    int e0 = ex, e1 = ex + v0;
    if (t * 2     < nk) { ptr[base + t * 2]     = e0; lfill[t * 2]     = e0; }
    if (t * 2 + 1 < nk) { ptr[base + t * 2 + 1] = e1; lfill[t * 2 + 1] = e1; }
    __syncthreads();
    for (int i = t; i < c; i += 512) {
        int2 ed = seg[i];
        if (ed.x >= 0) {
            int pos = atomicAdd(&lfill[ed.x - base], 1);
            adj[pos] = ed.y;
        }
    }
}

// ---------------- R23: prep = weight pre-scatter + zeroing only ----------------

__global__ void k_prep(int* __restrict__ zmem,
                       const float* W0l, const float* W0r, const float* W1l,
                       const float* W1r, const float* W2l, const float* W2r,
                       const float* W3l, const float* W3r, const float* W4l,
                       const float* W4r, ushort* __restrict__ Bpk) {
    int bid = blockIdx.x;
    int t   = threadIdx.x;
    if (bid < 640) {
        int idx = bid * 256 + t;  // 0..5*32768-1
        if (idx >= 5 * 32768) return;
        int c = idx >> 15, r = idx & 32767;
        const float* Wl = (c == 0 ? W0l : c == 1 ? W1l : c == 2 ? W2l : c == 3 ? W3l : W4l);
        const float* Wr = (c == 0 ? W0r : c == 1 ? W1r : c == 2 ? W2r : c == 3 ? W3r : W4r);
        int n = r & 255, k = r >> 8;
        float w = (n < H) ? Wl[k * H + n] : Wr[k * H + (n - H)];
        int q = k >> 5, g = (k >> 3) & 3, j = k & 7;
        int off = ((q * 4 + g) * 256 + n) * 8 + j;
        ushort h = f2bf(w);
        ushort* bh = Bpk + (size_t)c * 65536;
        bh[off]         = h;
        bh[32768 + off] = f2bf(w - bf2f(h));
        return;
    }
    int tid = (bid - 640) * 256 + t;
    if (tid < NG * H + 2 * NB) zmem[tid] = 0;   // gbuf + gcnt + rcnt
}

// ---------------- R23: layer-1 GEMM directly from x (f32), split in LDS ----------------
// staging: 4 threads/row load 8x float4 each, f2bf hi/lo split into the
// R13 [2][64][136] tile (same split as the old k_prep; bit-identical).
// gemm body = R13 LDS-read version (proven pre-R14).

__global__ __launch_bounds__(256) void k_gemm0(
    const float* __restrict__ x,
    const ushort* __restrict__ Bh, const ushort* __restrict__ Bl,
    ushort* __restrict__ z, ushort* __restrict__ yb) {
    __shared__ ushort Ash[2][64][136];   // 34.8 KB
    int t = threadIdx.x;
    int rowBase = blockIdx.x * 64;
    {
        int row = t >> 2;                 // 0..63
        int cs  = (t & 3) * 32;           // col segment base
        int grow = rowBase + row;
        if (grow > N_NODES - 1) grow = N_NODES - 1;
        const float4* src = (const float4*)(x + (size_t)grow * H + cs);
        ushort* dh = &Ash[0][row][cs];
        ushort* dl = &Ash[1][row][cs];
#pragma unroll
        for (int i = 0; i < 8; ++i) {
            float4 v = src[i];
            ushort4 hh, ll;
            hh.x = f2bf(v.x); ll.x = f2bf(v.x - bf2f(hh.x));
            hh.y = f2bf(v.y); ll.y = f2bf(v.y - bf2f(hh.y));
            hh.z = f2bf(v.z); ll.z = f2bf(v.z - bf2f(hh.z));
            hh.w = f2bf(v.w); ll.w = f2bf(v.w - bf2f(hh.w));
            *(ushort4*)(dh + i * 4) = hh;
            *(ushort4*)(dl + i * 4) = ll;
        }
    }
    __syncthreads();

    int wave = t >> 6, lane = t & 63;
    int m16 = lane & 15, q4 = lane >> 4;
    int n0 = wave * 64;

    f32x4 acc[4][4];
#pragma unroll
    for (int r = 0; r < 4; ++r)
#pragma unroll
        for (int c = 0; c < 4; ++c) {
            acc[r][c][0] = 0.f; acc[r][c][1] = 0.f;
            acc[r][c][2] = 0.f; acc[r][c][3] = 0.f;
        }

    for (int q = 0; q < 4; ++q) {
        short8 bh_[4], bl_[4], ah_[4], al_[4];
#pragma unroll
        for (int c = 0; c < 4; ++c) {
            int boff = ((q * 4 + q4) * 256 + n0 + c * 16 + m16) * 8;
            bh_[c] = *(const short8*)(Bh + boff);
            bl_[c] = *(const short8*)(Bl + boff);
        }
#pragma unroll
        for (int r = 0; r < 4; ++r) {
            ah_[r] = *(const short8*)&Ash[0][r * 16 + m16][q * 32 + q4 * 8];
            al_[r] = *(const short8*)&Ash[1][r * 16 + m16][q * 32 + q4 * 8];
        }
#pragma unroll
        for (int r = 0; r < 4; ++r)
#pragma unroll
            for (int c = 0; c < 4; ++c) {
                acc[r][c] = __builtin_amdgcn_mfma_f32_16x16x32_bf16(
                    ah_[r], bh_[c], acc[r][c], 0, 0, 0);
                acc[r][c] = __builtin_amdgcn_mfma_f32_16x16x32_bf16(
                    ah_[r], bl_[c], acc[r][c], 0, 0, 0);
                acc[r][c] = __builtin_amdgcn_mfma_f32_16x16x32_bf16(
                    al_[r], bh_[c], acc[r][c], 0, 0, 0);
            }
    }

    // C/D layout: col=lane&15, row=(lane>>4)*4+reg (m89-verified)
#pragma unroll
    for (int r = 0; r < 4; ++r)
#pragma unroll
        for (int c = 0; c < 4; ++c) {
            int col = n0 + c * 16 + m16;
            ushort* op = (col < H) ? (z + col) : (yb + (col - H));
#pragma unroll
            for (int j = 0; j < 4; ++j) {
                int gr = rowBase + r * 16 + q4 * 4 + j;
                if (gr < N_NODES) op[(size_t)gr * H] = f2bf(acc[r][c][j]);
            }
        }
}

// ---------------- R22: fused agg(L)+gemm(L+1), 32 rows, 512 threads ----------------

__global__ __launch_bounds__(512, 6) void k_fused2(
    const ushort* __restrict__ zin, const ushort* __restrict__ yin,
    ushort* __restrict__ zout, ushort* __restrict__ yout,
    const int* __restrict__ ptr, const int* __restrict__ adj,
    const float* __restrict__ bl,
    const ushort* __restrict__ Bh, const ushort* __restrict__ Blw,
    int norm) {
    __shared__ ushort Ash[2][32][136];   // 17.4 KB
    int t = threadIdx.x;
    int rowBase = blockIdx.x * 32;
    int sl  = t & 15;
    int row = t >> 4;                    // 0..31

    // ---- AGG phase (layer L): R18 body, one node per 16-lane group ----
    {
        int node = rowBase + row;
        if (node > N_NODES - 1) node = N_NODES - 1;   // clamp (dup; C-write guarded)
        int beg = ptr[node], end = ptr[node + 1];
        int deg = end - beg;
        const ushort* zrow = zin + sl * 8;
        float a[8];
#pragma unroll
        for (int k = 0; k < 8; ++k) a[k] = 0.f;

        for (int base = 0; base < deg; base += 16) {
            int m = deg - base;
            if (m > 16) m = 16;
            int idx = (sl < m) ? adj[beg + base + sl] : 0;
#pragma unroll
            for (int half = 0; half < 2; ++half) {
                int mh = m - half * 8;
                if (mh <= 0) continue;
                if (mh > 8) mh = 8;
                int hb = half * 8;
                short8 v[8];
#pragma unroll
                for (int jj = 0; jj < 8; ++jj) {
                    int nj = __shfl(idx, hb + jj, 16);
                    if (jj < mh) v[jj] = *(const short8*)(zrow + (size_t)nj * H);
                }
                if (mh == 8) {
#pragma unroll
                    for (int k = 0; k < 8; ++k)
                        a[k] += ((bf2f((ushort)v[0][k]) + bf2f((ushort)v[1][k])) +
                                 (bf2f((ushort)v[2][k]) + bf2f((ushort)v[3][k]))) +
                                ((bf2f((ushort)v[4][k]) + bf2f((ushort)v[5][k])) +
                                 (bf2f((ushort)v[6][k]) + bf2f((ushort)v[7][k])));
                } else if (mh >= 4) {
#pragma unroll
                    for (int k = 0; k < 8; ++k)
                        a[k] += (bf2f((ushort)v[0][k]) + bf2f((ushort)v[1][k])) +
                                (bf2f((ushort)v[2][k]) + bf2f((ushort)v[3][k]));
                    if (mh > 4) {
#pragma unroll
                        for (int k = 0; k < 8; ++k) a[k] += bf2f((ushort)v[4][k]);
                    }
                    if (mh > 5) {
#pragma unroll
                        for (int k = 0; k < 8; ++k) a[k] += bf2f((ushort)v[5][k]);
                    }
                    if (mh > 6) {
#pragma unroll
                        for (int k = 0; k < 8; ++k) a[k] += bf2f((ushort)v[6][k]);
                    }
                } else {
                    if (mh > 0) {
#pragma unroll
                        for (int k = 0; k < 8; ++k) a[k] += bf2f((ushort)v[0][k]);
                    }
                    if (mh > 1) {
#pragma unroll
                        for (int k = 0; k < 8; ++k) a[k] += bf2f((ushort)v[1][k]);
                    }
                    if (mh > 2) {
#pragma unroll
                        for (int k = 0; k < 8; ++k) a[k] += bf2f((ushort)v[2][k]);
                    }
                }
            }
        }

        float inv = 1.0f / (float)(deg > 1 ? deg : 1);
        short8 yv = *(const short8*)(yin + (size_t)node * H + sl * 8);
        float4 bva = *(const float4*)(bl + sl * 8);
        float4 bvb = *(const float4*)(bl + sl * 8 + 4);
        float vv[8];
        vv[0] = a[0] * inv + bva.x + bf2f((ushort)yv[0]);
        vv[1] = a[1] * inv + bva.y + bf2f((ushort)yv[1]);
        vv[2] = a[2] * inv + bva.z + bf2f((ushort)yv[2]);
        vv[3] = a[3] * inv + bva.w + bf2f((ushort)yv[3]);
        vv[4] = a[4] * inv + bvb.x + bf2f((ushort)yv[4]);
        vv[5] = a[5] * inv + bvb.y + bf2f((ushort)yv[5]);
        vv[6] = a[6] * inv + bvb.z + bf2f((ushort)yv[6]);
        vv[7] = a[7] * inv + bvb.w + bf2f((ushort)yv[7]);
        if (norm) {
            float ss = 0.f;
#pragma unroll
            for (int k = 0; k < 8; ++k) ss += vv[k] * vv[k];
#pragma unroll
            for (int mm = 1; mm < 16; mm <<= 1) ss += __shfl_xor(ss, mm, 16);
            float n2 = 1.0f / fmaxf(sqrtf(ss), 1e-12f);
#pragma unroll
            for (int k = 0; k < 8; ++k) vv[k] *= n2;
        }
        short8 ho, lo8;
#pragma unroll
        for (int k = 0; k < 8; ++k) {
            ushort hh = f2bf(vv[k]);
            ho[k]  = (short)hh;
            lo8[k] = (short)f2bf(vv[k] - bf2f(hh));
        }
        *(short8*)&Ash[0][row][sl * 8] = ho;     // h stays in LDS
        *(short8*)&Ash[1][row][sl * 8] = lo8;
    }
    __syncthreads();

    // ---- GEMM phase (layer L+1): 8 waves over 32x256 output ----
    int wave = t >> 6, lane = t & 63;
    int m16 = lane & 15, q4 = lane >> 4;
    int wr = wave & 1;                   // row tile (16 rows)
    int n0 = (wave >> 1) * 64;           // col group

    f32x4 acc[4];
#pragma unroll
    for (int c = 0; c < 4; ++c) {
        acc[c][0] = 0.f; acc[c][1] = 0.f; acc[c][2] = 0.f; acc[c][3] = 0.f;
    }

    for (int q = 0; q < 4; ++q) {
        short8 ah_ = *(const short8*)&Ash[0][wr * 16 + m16][q * 32 + q4 * 8];
        short8 al_ = *(const short8*)&Ash[1][wr * 16 + m16][q * 32 + q4 * 8];
#pragma unroll
        for (int c = 0; c < 4; ++c) {
            int boff = ((q * 4 + q4) * 256 + n0 + c * 16 + m16) * 8;
            short8 bh_ = *(const short8*)(Bh + boff);
            short8 bl_ = *(const short8*)(Blw + boff);
            acc[c] = __builtin_amdgcn_mfma_f32_16x16x32_bf16(ah_, bh_, acc[c], 0, 0, 0);
            acc[c] = __builtin_amdgcn_mfma_f32_16x16x32_bf16(ah_, bl_, acc[c], 0, 0, 0);
            acc[c] = __builtin_amdgcn_mfma_f32_16x16x32_bf16(al_, bh_, acc[c], 0, 0, 0);
        }
    }

    // C/D layout: col=lane&15, row=(lane>>4)*4+reg (m89-verified)
#pragma unroll
    for (int c = 0; c < 4; ++c) {
        int col = n0 + c * 16 + m16;
        ushort* op = (col < H) ? (zout + col) : (yout + (col - H));
#pragma unroll
        for (int j = 0; j < 4; ++j) {
            int gr = rowBase + wr * 16 + q4 * 4 + j;
            if (gr < N_NODES) op[(size_t)gr * H] = f2bf(acc[c][j]);
        }
    }
}

// ---------------- R23: final agg(L=6)+norm fused with global_add_pool ----------------
// R18 agg body -> vv (f32, no hi/lo re-split); per-graph LDS slots (batch
// sorted; block of 16 nodes spans ~1-2 graphs), then one atomicAdd per
// (slot,col) to gbuf. Overflow (gl>=16) falls back to direct global adds.

__global__ __launch_bounds__(256, 8) void k_aggpool(
    const ushort* __restrict__ z, const ushort* __restrict__ yb,
    const int* __restrict__ ptr, const int* __restrict__ adj,
    const float* __restrict__ bl, const int* __restrict__ batch,
    float* __restrict__ g) {
    __shared__ float accs[16][H];        // 8 KB
    __shared__ int gfirst;
    int t = threadIdx.x;
    int node0 = blockIdx.x * 16;
    int gtid = blockIdx.x * 256 + t;
    int node = gtid >> 4;                // 16 lanes per node
    int sl   = t & 15;
    for (int i = t; i < 16 * H; i += 256) ((float*)accs)[i] = 0.f;
    if (t == 0) gfirst = batch[node0 < N_NODES ? node0 : N_NODES - 1];
    __syncthreads();

    if (node < N_NODES) {
        int beg = ptr[node], end = ptr[node + 1];
        int deg = end - beg;
        const ushort* zrow = z + sl * 8;
        float a[8];
#pragma unroll
        for (int k = 0; k < 8; ++k) a[k] = 0.f;

        for (int base = 0; base < deg; base += 16) {
            int m = deg - base;
            if (m > 16) m = 16;
            int idx = (sl < m) ? adj[beg + base + sl] : 0;
#pragma unroll
            for (int half = 0; half < 2; ++half) {
                int mh = m - half * 8;
                if (mh <= 0) continue;
                if (mh > 8) mh = 8;
                int hb = half * 8;
                short8 v[8];
#pragma unroll
                for (int jj = 0; jj < 8; ++jj) {
                    int nj = __shfl(idx, hb + jj, 16);
                    if (jj < mh) v[jj] = *(const short8*)(zrow + (size_t)nj * H);
                }
                if (mh == 8) {
#pragma unroll
                    for (int k = 0; k < 8; ++k)
                        a[k] += ((bf2f((ushort)v[0][k]) + bf2f((ushort)v[1][k])) +
                                 (bf2f((ushort)v[2][k]) + bf2f((ushort)v[3][k]))) +
                                ((bf2f((ushort)v[4][k]) + bf2f((ushort)v[5][k])) +
                                 (bf2f((ushort)v[6][k]) + bf2f((ushort)v[7][k])));
                } else if (mh >= 4) {
#pragma unroll
                    for (int k = 0; k < 8; ++k)
                        a[k] += (bf2f((ushort)v[0][k]) + bf2f((ushort)v[1][k])) +
                                (bf2f((ushort)v[2][k]) + bf2f((ushort)v[3][k]));
                    if (mh > 4) {
#pragma unroll
                        for (int k = 0; k < 8; ++k) a[k] += bf2f((ushort)v[4][k]);
                    }
                    if (mh > 5) {
#pragma unroll
                        for (int k = 0; k < 8; ++k) a[k] += bf2f((ushort)v[5][k]);
                    }
                    if (mh > 6) {
#pragma unroll
                        for (int k = 0; k < 8; ++k) a[k] += bf2f((ushort)v[6][k]);
                    }
                } else {
                    if (mh > 0) {
#pragma unroll
                        for (int k = 0; k < 8; ++k) a[k] += bf2f((ushort)v[0][k]);
                    }
                    if (mh > 1) {
#pragma unroll
                        for (int k = 0; k < 8; ++k) a[k] += bf2f((ushort)v[1][k]);
                    }
                    if (mh > 2) {
#pragma unroll
                        for (int k = 0; k < 8; ++k) a[k] += bf2f((ushort)v[2][k]);
                    }
                }
            }
        }

        float inv = 1.0f / (float)(deg > 1 ? deg : 1);
        short8 yv = *(const short8*)(yb + (size_t)node * H + sl * 8);
        float4 bva = *(const float4*)(bl + sl * 8);
        float4 bvb = *(const float4*)(bl + sl * 8 + 4);
        float vv[8];
        vv[0] = a[0] * inv + bva.x + bf2f((ushort)yv[0]);
        vv[1] = a[1] * inv + bva.y + bf2f((ushort)yv[1]);
        vv[2] = a[2] * inv + bva.z + bf2f((ushort)yv[2]);
        vv[3] = a[3] * inv + bva.w + bf2f((ushort)yv[3]);
        vv[4] = a[4] * inv + bvb.x + bf2f((ushort)yv[4]);
        vv[5] = a[5] * inv + bvb.y + bf2f((ushort)yv[5]);
        vv[6] = a[6] * inv + bvb.z + bf2f((ushort)yv[6]);
        vv[7] = a[7] * inv + bvb.w + bf2f((ushort)yv[7]);
        {   // final layer norm=1
            float ss = 0.f;
#pragma unroll
            for (int k = 0; k < 8; ++k) ss += vv[k] * vv[k];
#pragma unroll
            for (int mm = 1; mm < 16; mm <<= 1) ss += __shfl_xor(ss, mm, 16);
            float n2 = 1.0f / fmaxf(sqrtf(ss), 1e-12f);
#pragma unroll
            for (int k = 0; k < 8; ++k) vv[k] *= n2;
        }
        int gl = batch[node] - gfirst;
        if (gl < 16) {
#pragma unroll
            for (int k = 0; k < 8; ++k) atomicAdd(&accs[gl][sl * 8 + k], vv[k]);
        } else {
#pragma unroll
            for (int k = 0; k < 8; ++k)
                atomicAdd(&g[(size_t)batch[node] * H + sl * 8 + k], vv[k]);
        }
    }
    __syncthreads();

    int lastnode = node0 + 15;
    if (lastnode > N_NODES - 1) lastnode = N_NODES - 1;
    int nsl = batch[lastnode] - gfirst + 1;
    if (nsl > 16) nsl = 16;
    for (int i = t; i < nsl * H; i += 256)
        atomicAdd(&g[(size_t)(gfirst + i / H) * H + (i % H)], accs[i / H][i % H]);
}

// ---------------- MLP head ----------------

__global__ void k_mlp(const float* __restrict__ g, const float* __restrict__ W0,
                      const float* __restrict__ b0, const float* __restrict__ W1,
                      const float* __restrict__ b1, const float* __restrict__ Wh,
                      const float* __restrict__ bh, float* __restrict__ out) {
    int gi = blockIdx.x;
    int t  = threadIdx.x;  // 0..127
    __shared__ float buf0[H];
    __shared__ float buf1[H];
    __shared__ float red[2];

    float acc = b0[t];
    for (int k = 0; k < H; ++k) acc += g[gi * H + k] * W0[k * H + t];
    buf0[t] = fmaxf(acc, 0.f);
    __syncthreads();

    acc = b1[t];
    for (int k = 0; k < H; ++k) acc += buf0[k] * W1[k * H + t];
    buf1[t] = fmaxf(acc, 0.f);
    __syncthreads();

    float p = buf1[t] * Wh[t];
    for (int m = 1; m < 64; m <<= 1) p += __shfl_xor(p, m, 64);
    if ((t & 63) == 0) red[t >> 6] = p;
    __syncthreads();
    if (t == 0) out[gi] = red[0] + red[1] + bh[0];
}

// ---------------- driver ----------------

extern "C" void kernel_launch(void* const* d_in, const int* in_sizes, int n_in,
                              void* d_out, int out_size, void* d_ws, size_t ws_size,
                              hipStream_t stream) {
    const float* x     = (const float*)d_in[0];
    const int*   eic   = (const int*)d_in[1];
    const int*   eid   = (const int*)d_in[2];
    const int*   eit   = (const int*)d_in[3];
    const int*   batch = (const int*)d_in[4];
    const float* cW[5][3];
    for (int c = 0; c < 5; ++c) {
        cW[c][0] = (const float*)d_in[5 + c * 3 + 0];  // Wl
        cW[c][1] = (const float*)d_in[5 + c * 3 + 1];  // bl
        cW[c][2] = (const float*)d_in[5 + c * 3 + 2];  // Wr
    }
    const float* l0_W = (const float*)d_in[20];
    const float* l0_b = (const float*)d_in[21];
    const float* l1_W = (const float*)d_in[22];
    const float* l1_b = (const float*)d_in[23];
    const float* hd_W = (const float*)d_in[24];
    const float* hd_b = (const float*)d_in[25];
    float* outp = (float*)d_out;

    const size_t NH = (size_t)N_NODES * H;
    ushort* zb0 = (ushort*)d_ws;               // ping
    ushort* yb0 = zb0 + NH;
    ushort* zb1 = yb0 + NH;                    // pong
    ushort* yb1 = zb1 + NH;
    ushort* Bpk = yb1 + NH;                    // 5 convs x 2 planes x 32768
    float*  gbuf = (float*)(Bpk + 5 * 2 * 32768);
    int* gcnt = (int*)(gbuf + (size_t)NG * H);     // zeroed by k_prep
    int* rcnt = gcnt + NB;                         // zeroed by k_prep
    int* ptr_all = rcnt + NB;                      // N3+1 ints (persistent)
    int* adj_all = ptr_all + (N3 + 1);             // 3*NE ints (persistent)
    // CSR-build scratch inside zb0+yb0 (dead until gemm0, stream-ordered):
    //   bucket[NB*CAP2 int2] (64B-aligned at zb0) = 22.88 MB < 25.6MB
    int2* bucket = (int2*)zb0;

    dim3 b256(256);

    // prep: weight pre-scatter (blocks<640) + gbuf/gcnt/rcnt zeroing
    k_prep<<<dim3(640 + 34), b256, 0, stream>>>(
        (int*)gbuf,
        cW[0][0], cW[0][2], cW[1][0], cW[1][2], cW[2][0], cW[2][2],
        cW[3][0], cW[3][2], cW[4][0], cW[4][2], Bpk);

    // CSR build: bucketize -> per-bucket (total-scan + ptr + scatter)
    k_bucketize<<<dim3(3 * BPS), b256, 0, stream>>>(eic, eid, eit, gcnt, rcnt, bucket);
    k_scatter2<<<dim3(NB), dim3(512), 0, stream>>>(bucket, gcnt, rcnt, ptr_all, adj_all);

    const int L_set[7]  = {1, 0, 0, 2, 1, 0, 0};
    const int L_conv[7] = {0, 1, 1, 2, 3, 4, 4};
    const int L_norm[7] = {1, 1, 1, 0, 1, 1, 1};

    dim3 gGemm((N_NODES + 63) / 64);         // 782
    dim3 gFused((N_NODES + 31) / 32);        // 1563
    dim3 gAggP((N_NODES * 16 + 255) / 256);  // 3125 (final layer)

    // layer 1 GEMM directly from x -> pair0
    k_gemm0<<<gGemm, b256, 0, stream>>>(x, Bpk + (size_t)L_conv[0] * 65536,
                                        Bpk + (size_t)L_conv[0] * 65536 + 32768,
                                        zb0, yb0);

    // fused agg(L)+gemm(L+1), L=0..5, ping-pong z/y pairs
    for (int L = 0; L < 6; ++L) {
        ushort* zi = (L & 1) ? zb1 : zb0;
        ushort* yi = (L & 1) ? yb1 : yb0;
        ushort* zo = (L & 1) ? zb0 : zb1;
        ushort* yo = (L & 1) ? yb0 : yb1;
        const ushort* Bh = Bpk + (size_t)L_conv[L + 1] * 65536;
        const ushort* Bl = Bh + 32768;
        k_fused2<<<gFused, dim3(512), 0, stream>>>(zi, yi, zo, yo,
                                                   ptr_all + L_set[L] * N_NODES,
                                                   adj_all, cW[L_conv[L]][1], Bh, Bl,
                                                   L_norm[L]);
    }

    // final agg (L=6) reads pair0 (L=6 even) fused with global_add_pool
    k_aggpool<<<gAggP, b256, 0, stream>>>(zb0, yb0, ptr_all + L_set[6] * N_NODES,
                                          adj_all, cW[L_conv[6]][1], batch, gbuf);

    k_mlp<<<dim3(NG), dim3(H), 0, stream>>>(gbuf, l0_W, l0_b, l1_W, l1_b, hd_W, hd_b,
                                            outp);
}

// Round 12
// 428.538 us; speedup vs baseline: 1.2912x; 1.1008x over previous
//
#include <hip/hip_runtime.h>
#include <hip/hip_bf16.h>

// ValueNet: 7x SAGEConv(mean) + global_add_pool + MLP head.
// N=50000 nodes, E=600000 edges/set, H=128, G=64 graphs.
//
// out_i = mean_j(z_j) + bl + y_i,  z = h@Wl, y = h@Wr (linearity of mean).
// GEMM on MFMA bf16 with split precision (hi+lo planes, 3 MFMAs: hh+hl+lh).
// z,y stored bf16.
//
// R24: (a) k_fused2 gemm phase: waves own 32 cols x BOTH 16-row tiles ->
//      every B fragment pair feeds 2 MFMAs -> B line requests HALVED
//      (~3.2M -> 1.6M/layer; gather is 1.2M). Same MFMA count and
//      per-output order (bit-identical).
//      (b) k_aggpool: LDS atomics -> race-free per-node LDS writes +
//      128-thread column reduce with graph-change flush (batch sorted,
//      ~1.02 flushes/col). Removes 16-way LDS atomic serialization.
// R23: k_gemm0 reads x f32 directly (split in LDS); k_aggpool fuses final
//      agg+norm+pool; k_prep = weights + zeroing only.
// R22: fused agg(L)+gemm(L+1), 32 rows/512 thr, launch_bounds(512,6);
//      z/y ping-pong.
// R18: agg 8-in-flight halves (v[8]) everywhere.
// CSR build (R12): LDS-staged bucket sort, NO per-key global atomics.
//
// Agg gather floor (R13-R20): ~36-40us/layer invariant to instructions,
// L2 residency, ILP, occupancy, fusion-bytes. Do not re-attack without a
// new mechanism (R24a targets the B-request side, not the gather).

constexpr int N_NODES = 50000;
constexpr int NE      = 600000;
constexpr int H       = 128;
constexpr int NG      = 64;
constexpr int N3      = 3 * N_NODES;            // 150000

constexpr int NB   = (N3 + 1023) >> 10;          // 147 buckets (1024 keys each)
constexpr int EPB  = 2048;                       // edges per block (phase A)
constexpr int BPS  = (NE + EPB - 1) / EPB;       // 293 blocks per edge set
constexpr int CAP2 = 19456;                      // slots/bucket (exp ~15.4k padded; mult of 8)

typedef __attribute__((ext_vector_type(8))) short short8;
typedef __attribute__((ext_vector_type(4))) float f32x4;

__device__ __forceinline__ ushort f2bf(float f) {  // RNE float->bf16
    uint x = __float_as_uint(f);
    return (ushort)((x + 0x7FFFu + ((x >> 16) & 1u)) >> 16);
}
__device__ __forceinline__ float bf2f(ushort u) {
    return __uint_as_float(((uint)u) << 16);
}

// ---------------- Phase A: LDS-staged bucketize (padded, sentinel-filled) ----------------

__global__ __launch_bounds__(256) void k_bucketize(
    const int* __restrict__ e0, const int* __restrict__ e1,
    const int* __restrict__ e2, int* __restrict__ gcnt,
    int* __restrict__ rcnt, int2* __restrict__ bucket) {
    __shared__ int hist[NB];
    __shared__ int basearr[NB];
    __shared__ int cur[NB];
    __shared__ int gposs[NB];
    __shared__ int2 stage[EPB];
    __shared__ int dstoff[EPB];

    int t = threadIdx.x;
    int s = blockIdx.x / BPS;
    int w = blockIdx.x - s * BPS;
    const int* ep = (s == 0 ? e0 : (s == 1 ? e1 : e2));
    int eBase = w * EPB;
    int m = NE - eBase;
    if (m > EPB) m = EPB;

    for (int i = t; i < NB; i += 256) hist[i] = 0;
    __syncthreads();

    // pass 1: read edges into regs, LDS histogram
    int myk[EPB / 256], mys[EPB / 256];
#pragma unroll
    for (int k = 0; k < EPB / 256; ++k) {
        int i = t + 256 * k;
        if (i < m) {
            int d   = ep[NE + eBase + i];
            int src = ep[eBase + i];
            int key = s * N_NODES + d;
            myk[k] = key; mys[k] = src;
            atomicAdd(&hist[key >> 10], 1);
        } else {
            myk[k] = -1;
        }
    }
    __syncthreads();

    if (t == 0) {  // serial scan over 147 entries (cheap)
        int run = 0;
        for (int b = 0; b < NB; ++b) { basearr[b] = run; run += hist[b]; }
    }
    __syncthreads();

    if (t < NB) {  // padded reserve: ONE atomic per (block,bucket); runs 64B-aligned
        int h = hist[t];
        int p = (h + 7) & ~7;
        gposs[t] = p ? atomicAdd(&gcnt[t], p) : 0;
        if (h) atomicAdd(&rcnt[t], h);
        cur[t] = 0;
    }
    __syncthreads();

    // pass 2: scatter into LDS stage in bucket order; record dense dst offsets
#pragma unroll
    for (int k = 0; k < EPB / 256; ++k) {
        if (myk[k] >= 0) {
            int b  = myk[k] >> 10;
            int sl = atomicAdd(&cur[b], 1);
            int p  = basearr[b] + sl;
            stage[p]  = make_int2(myk[k], mys[k]);
            dstoff[p] = b * CAP2 + gposs[b] + sl;
        }
    }
    __syncthreads();

    // copyout: consecutive stage slots within a run -> consecutive global addrs
    for (int i = t; i < m; i += 256) bucket[dstoff[i]] = stage[i];
    // sentinel-fill the pad slots (<=7 per (block,bucket), same lines as runs)
    for (int i = t; i < NB * 8; i += 256) {
        int b = i >> 3, j = i & 7;
        int h = hist[b];
        int p = (h + 7) & ~7;
        if (h + j < p)
            bucket[(size_t)b * CAP2 + gposs[b] + h + j] = make_int2(-1, 0);
    }
}

// ---------------- Phase B: per-bucket hist + scan -> ptr slice + adj scatter ----------------

__global__ __launch_bounds__(512) void k_scatter2(const int2* __restrict__ bucket,
                                                  const int* __restrict__ gcnt,
                                                  const int* __restrict__ rcnt,
                                                  int* __restrict__ ptr,
                                                  int* __restrict__ adj) {
    int b = blockIdx.x;           // 0..NB-1
    int base = b << 10;
    int nk = N3 - base;
    if (nk > 1024) nk = 1024;
    __shared__ int lh[1024];
    __shared__ int lsum[512];
    __shared__ int lfill[1024];
    __shared__ int bb;
    int t = threadIdx.x;

    // exclusive prefix of real bucket totals -> bb (value at index b only)
    int rv = (t < NB) ? rcnt[t] : 0;
    lsum[t] = rv;
    __syncthreads();
    for (int off = 1; off < 512; off <<= 1) {
        int u = (t >= off) ? lsum[t - off] : 0;
        __syncthreads();
        if (t >= off) lsum[t] += u;
        __syncthreads();
    }
    if (t == b) bb = lsum[t] - rv;
    if (b == 0 && t == 0) ptr[N3] = 3 * NE;
    for (int i = t; i < 1024; i += 512) lh[i] = 0;
    __syncthreads();

    int c = gcnt[b];              // padded slot count actually used
    const int2* seg = bucket + (size_t)b * CAP2;
    for (int i = t; i < c; i += 512) {
        int k = seg[i].x;
        if (k >= 0) atomicAdd(&lh[k - base], 1);
    }
    __syncthreads();
    // exclusive 1024-scan: 2 seq per thread + 512 Hillis-Steele
    int v0 = lh[t * 2], v1 = lh[t * 2 + 1];
    int ts = v0 + v1;
    lsum[t] = ts;
    __syncthreads();
    for (int off = 1; off < 512; off <<= 1) {
        int u = (t >= off) ? lsum[t - off] : 0;
        __syncthreads();
        if (t >= off) lsum[t] += u;
        __syncthreads();
    }
    int ex = lsum[t] - ts + bb;
    int e0 = ex, e1 = ex + v0;
    if (t * 2     < nk) { ptr[base + t * 2]     = e0; lfill[t * 2]     = e0; }
    if (t * 2 + 1 < nk) { ptr[base + t * 2 + 1] = e1; lfill[t * 2 + 1] = e1; }
    __syncthreads();
    for (int i = t; i < c; i += 512) {
        int2 ed = seg[i];
        if (ed.x >= 0) {
            int pos = atomicAdd(&lfill[ed.x - base], 1);
            adj[pos] = ed.y;
        }
    }
}

// ---------------- R23: prep = weight pre-scatter + zeroing only ----------------

__global__ void k_prep(int* __restrict__ zmem,
                       const float* W0l, const float* W0r, const float* W1l,
                       const float* W1r, const float* W2l, const float* W2r,
                       const float* W3l, const float* W3r, const float* W4l,
                       const float* W4r, ushort* __restrict__ Bpk) {
    int bid = blockIdx.x;
    int t   = threadIdx.x;
    if (bid < 640) {
        int idx = bid * 256 + t;  // 0..5*32768-1
        if (idx >= 5 * 32768) return;
        int c = idx >> 15, r = idx & 32767;
        const float* Wl = (c == 0 ? W0l : c == 1 ? W1l : c == 2 ? W2l : c == 3 ? W3l : W4l);
        const float* Wr = (c == 0 ? W0r : c == 1 ? W1r : c == 2 ? W2r : c == 3 ? W3r : W4r);
        int n = r & 255, k = r >> 8;
        float w = (n < H) ? Wl[k * H + n] : Wr[k * H + (n - H)];
        int q = k >> 5, g = (k >> 3) & 3, j = k & 7;
        int off = ((q * 4 + g) * 256 + n) * 8 + j;
        ushort h = f2bf(w);
        ushort* bh = Bpk + (size_t)c * 65536;
        bh[off]         = h;
        bh[32768 + off] = f2bf(w - bf2f(h));
        return;
    }
    int tid = (bid - 640) * 256 + t;
    if (tid < NG * H + 2 * NB) zmem[tid] = 0;   // gbuf + gcnt + rcnt
}

// ---------------- R23: layer-1 GEMM directly from x (f32), split in LDS ----------------

__global__ __launch_bounds__(256) void k_gemm0(
    const float* __restrict__ x,
    const ushort* __restrict__ Bh, const ushort* __restrict__ Bl,
    ushort* __restrict__ z, ushort* __restrict__ yb) {
    __shared__ ushort Ash[2][64][136];   // 34.8 KB
    int t = threadIdx.x;
    int rowBase = blockIdx.x * 64;
    {
        int row = t >> 2;                 // 0..63
        int cs  = (t & 3) * 32;           // col segment base
        int grow = rowBase + row;
        if (grow > N_NODES - 1) grow = N_NODES - 1;
        const float4* src = (const float4*)(x + (size_t)grow * H + cs);
        ushort* dh = &Ash[0][row][cs];
        ushort* dl = &Ash[1][row][cs];
#pragma unroll
        for (int i = 0; i < 8; ++i) {
            float4 v = src[i];
            ushort4 hh, ll;
            hh.x = f2bf(v.x); ll.x = f2bf(v.x - bf2f(hh.x));
            hh.y = f2bf(v.y); ll.y = f2bf(v.y - bf2f(hh.y));
            hh.z = f2bf(v.z); ll.z = f2bf(v.z - bf2f(hh.z));
            hh.w = f2bf(v.w); ll.w = f2bf(v.w - bf2f(hh.w));
            *(ushort4*)(dh + i * 4) = hh;
            *(ushort4*)(dl + i * 4) = ll;
        }
    }
    __syncthreads();

    int wave = t >> 6, lane = t & 63;
    int m16 = lane & 15, q4 = lane >> 4;
    int n0 = wave * 64;

    f32x4 acc[4][4];
#pragma unroll
    for (int r = 0; r < 4; ++r)
#pragma unroll
        for (int c = 0; c < 4; ++c) {
            acc[r][c][0] = 0.f; acc[r][c][1] = 0.f;
            acc[r][c][2] = 0.f; acc[r][c][3] = 0.f;
        }

    for (int q = 0; q < 4; ++q) {
        short8 bh_[4], bl_[4], ah_[4], al_[4];
#pragma unroll
        for (int c = 0; c < 4; ++c) {
            int boff = ((q * 4 + q4) * 256 + n0 + c * 16 + m16) * 8;
            bh_[c] = *(const short8*)(Bh + boff);
            bl_[c] = *(const short8*)(Bl + boff);
        }
#pragma unroll
        for (int r = 0; r < 4; ++r) {
            ah_[r] = *(const short8*)&Ash[0][r * 16 + m16][q * 32 + q4 * 8];
            al_[r] = *(const short8*)&Ash[1][r * 16 + m16][q * 32 + q4 * 8];
        }
#pragma unroll
        for (int r = 0; r < 4; ++r)
#pragma unroll
            for (int c = 0; c < 4; ++c) {
                acc[r][c] = __builtin_amdgcn_mfma_f32_16x16x32_bf16(
                    ah_[r], bh_[c], acc[r][c], 0, 0, 0);
                acc[r][c] = __builtin_amdgcn_mfma_f32_16x16x32_bf16(
                    ah_[r], bl_[c], acc[r][c], 0, 0, 0);
                acc[r][c] = __builtin_amdgcn_mfma_f32_16x16x32_bf16(
                    al_[r], bh_[c], acc[r][c], 0, 0, 0);
            }
    }

    // C/D layout: col=lane&15, row=(lane>>4)*4+reg (m89-verified)
#pragma unroll
    for (int r = 0; r < 4; ++r)
#pragma unroll
        for (int c = 0; c < 4; ++c) {
            int col = n0 + c * 16 + m16;
            ushort* op = (col < H) ? (z + col) : (yb + (col - H));
#pragma unroll
            for (int j = 0; j < 4; ++j) {
                int gr = rowBase + r * 16 + q4 * 4 + j;
                if (gr < N_NODES) op[(size_t)gr * H] = f2bf(acc[r][c][j]);
            }
        }
}

// ---------------- R22/R24: fused agg(L)+gemm(L+1), 32 rows, 512 threads ----------------
// R24 gemm phase: wave = 32 cols x BOTH row tiles -> B fragments reused 2x
// (B line requests halved). Same MFMA count and per-output order.

__global__ __launch_bounds__(512, 6) void k_fused2(
    const ushort* __restrict__ zin, const ushort* __restrict__ yin,
    ushort* __restrict__ zout, ushort* __restrict__ yout,
    const int* __restrict__ ptr, const int* __restrict__ adj,
    const float* __restrict__ bl,
    const ushort* __restrict__ Bh, const ushort* __restrict__ Blw,
    int norm) {
    __shared__ ushort Ash[2][32][136];   // 17.4 KB
    int t = threadIdx.x;
    int rowBase = blockIdx.x * 32;
    int sl  = t & 15;
    int row = t >> 4;                    // 0..31

    // ---- AGG phase (layer L): R18 body, one node per 16-lane group ----
    {
        int node = rowBase + row;
        if (node > N_NODES - 1) node = N_NODES - 1;   // clamp (dup; C-write guarded)
        int beg = ptr[node], end = ptr[node + 1];
        int deg = end - beg;
        const ushort* zrow = zin + sl * 8;
        float a[8];
#pragma unroll
        for (int k = 0; k < 8; ++k) a[k] = 0.f;

        for (int base = 0; base < deg; base += 16) {
            int m = deg - base;
            if (m > 16) m = 16;
            int idx = (sl < m) ? adj[beg + base + sl] : 0;
#pragma unroll
            for (int half = 0; half < 2; ++half) {
                int mh = m - half * 8;
                if (mh <= 0) continue;
                if (mh > 8) mh = 8;
                int hb = half * 8;
                short8 v[8];
#pragma unroll
                for (int jj = 0; jj < 8; ++jj) {
                    int nj = __shfl(idx, hb + jj, 16);
                    if (jj < mh) v[jj] = *(const short8*)(zrow + (size_t)nj * H);
                }
                if (mh == 8) {
#pragma unroll
                    for (int k = 0; k < 8; ++k)
                        a[k] += ((bf2f((ushort)v[0][k]) + bf2f((ushort)v[1][k])) +
                                 (bf2f((ushort)v[2][k]) + bf2f((ushort)v[3][k]))) +
                                ((bf2f((ushort)v[4][k]) + bf2f((ushort)v[5][k])) +
                                 (bf2f((ushort)v[6][k]) + bf2f((ushort)v[7][k])));
                } else if (mh >= 4) {
#pragma unroll
                    for (int k = 0; k < 8; ++k)
                        a[k] += (bf2f((ushort)v[0][k]) + bf2f((ushort)v[1][k])) +
                                (bf2f((ushort)v[2][k]) + bf2f((ushort)v[3][k]));
                    if (mh > 4) {
#pragma unroll
                        for (int k = 0; k < 8; ++k) a[k] += bf2f((ushort)v[4][k]);
                    }
                    if (mh > 5) {
#pragma unroll
                        for (int k = 0; k < 8; ++k) a[k] += bf2f((ushort)v[5][k]);
                    }
                    if (mh > 6) {
#pragma unroll
                        for (int k = 0; k < 8; ++k) a[k] += bf2f((ushort)v[6][k]);
                    }
                } else {
                    if (mh > 0) {
#pragma unroll
                        for (int k = 0; k < 8; ++k) a[k] += bf2f((ushort)v[0][k]);
                    }
                    if (mh > 1) {
#pragma unroll
                        for (int k = 0; k < 8; ++k) a[k] += bf2f((ushort)v[1][k]);
                    }
                    if (mh > 2) {
#pragma unroll
                        for (int k = 0; k < 8; ++k) a[k] += bf2f((ushort)v[2][k]);
                    }
                }
            }
        }

        float inv = 1.0f / (float)(deg > 1 ? deg : 1);
        short8 yv = *(const short8*)(yin + (size_t)node * H + sl * 8);
        float4 bva = *(const float4*)(bl + sl * 8);
        float4 bvb = *(const float4*)(bl + sl * 8 + 4);
        float vv[8];
        vv[0] = a[0] * inv + bva.x + bf2f((ushort)yv[0]);
        vv[1] = a[1] * inv + bva.y + bf2f((ushort)yv[1]);
        vv[2] = a[2] * inv + bva.z + bf2f((ushort)yv[2]);
        vv[3] = a[3] * inv + bva.w + bf2f((ushort)yv[3]);
        vv[4] = a[4] * inv + bvb.x + bf2f((ushort)yv[4]);
        vv[5] = a[5] * inv + bvb.y + bf2f((ushort)yv[5]);
        vv[6] = a[6] * inv + bvb.z + bf2f((ushort)yv[6]);
        vv[7] = a[7] * inv + bvb.w + bf2f((ushort)yv[7]);
        if (norm) {
            float ss = 0.f;
#pragma unroll
            for (int k = 0; k < 8; ++k) ss += vv[k] * vv[k];
#pragma unroll
            for (int mm = 1; mm < 16; mm <<= 1) ss += __shfl_xor(ss, mm, 16);
            float n2 = 1.0f / fmaxf(sqrtf(ss), 1e-12f);
#pragma unroll
            for (int k = 0; k < 8; ++k) vv[k] *= n2;
        }
        short8 ho, lo8;
#pragma unroll
        for (int k = 0; k < 8; ++k) {
            ushort hh = f2bf(vv[k]);
            ho[k]  = (short)hh;
            lo8[k] = (short)f2bf(vv[k] - bf2f(hh));
        }
        *(short8*)&Ash[0][row][sl * 8] = ho;     // h stays in LDS
        *(short8*)&Ash[1][row][sl * 8] = lo8;
    }
    __syncthreads();

    // ---- GEMM phase (layer L+1): 8 waves x (32 cols, 2 row tiles) ----
    int wave = t >> 6, lane = t & 63;
    int m16 = lane & 15, q4 = lane >> 4;
    int n0 = wave * 32;                  // 8 waves x 32 cols = 256

    f32x4 acc[2][2];
#pragma unroll
    for (int r = 0; r < 2; ++r)
#pragma unroll
        for (int c = 0; c < 2; ++c) {
            acc[r][c][0] = 0.f; acc[r][c][1] = 0.f;
            acc[r][c][2] = 0.f; acc[r][c][3] = 0.f;
        }

    for (int q = 0; q < 4; ++q) {
        short8 ah0 = *(const short8*)&Ash[0][m16][q * 32 + q4 * 8];
        short8 al0 = *(const short8*)&Ash[1][m16][q * 32 + q4 * 8];
        short8 ah1 = *(const short8*)&Ash[0][16 + m16][q * 32 + q4 * 8];
        short8 al1 = *(const short8*)&Ash[1][16 + m16][q * 32 + q4 * 8];
#pragma unroll
        for (int c = 0; c < 2; ++c) {
            int boff = ((q * 4 + q4) * 256 + n0 + c * 16 + m16) * 8;
            short8 bh_ = *(const short8*)(Bh + boff);
            short8 bl_ = *(const short8*)(Blw + boff);
            acc[0][c] = __builtin_amdgcn_mfma_f32_16x16x32_bf16(ah0, bh_, acc[0][c], 0, 0, 0);
            acc[0][c] = __builtin_amdgcn_mfma_f32_16x16x32_bf16(ah0, bl_, acc[0][c], 0, 0, 0);
            acc[0][c] = __builtin_amdgcn_mfma_f32_16x16x32_bf16(al0, bh_, acc[0][c], 0, 0, 0);
            acc[1][c] = __builtin_amdgcn_mfma_f32_16x16x32_bf16(ah1, bh_, acc[1][c], 0, 0, 0);
            acc[1][c] = __builtin_amdgcn_mfma_f32_16x16x32_bf16(ah1, bl_, acc[1][c], 0, 0, 0);
            acc[1][c] = __builtin_amdgcn_mfma_f32_16x16x32_bf16(al1, bh_, acc[1][c], 0, 0, 0);
        }
    }

    // C/D layout: col=lane&15, row=(lane>>4)*4+reg (m89-verified)
#pragma unroll
    for (int r = 0; r < 2; ++r)
#pragma unroll
        for (int c = 0; c < 2; ++c) {
            int col = n0 + c * 16 + m16;
            ushort* op = (col < H) ? (zout + col) : (yout + (col - H));
#pragma unroll
            for (int j = 0; j < 4; ++j) {
                int gr = rowBase + r * 16 + q4 * 4 + j;
                if (gr < N_NODES) op[(size_t)gr * H] = f2bf(acc[r][c][j]);
            }
        }
}

// ---------------- R24: final agg(L=6)+norm fused with global_add_pool ----------------
// R18 agg body -> vv (f32); per-NODE LDS rows (race-free), then 128-thread
// column reduce over the 16 nodes with graph-change flush (batch sorted,
// ~1.02 flushes/col).

__global__ __launch_bounds__(256, 8) void k_aggpool(
    const ushort* __restrict__ z, const ushort* __restrict__ yb,
    const int* __restrict__ ptr, const int* __restrict__ adj,
    const float* __restrict__ bl, const int* __restrict__ batch,
    float* __restrict__ g) {
    __shared__ float accs[16][H];        // 8 KB (per-node vv)
    __shared__ int gid[16];
    int t = threadIdx.x;
    int gtid = blockIdx.x * 256 + t;
    int node = gtid >> 4;                // 16 lanes per node
    int sl   = t & 15;
    int nib  = t >> 4;                   // node-in-block 0..15

    if (node < N_NODES) {
        int beg = ptr[node], end = ptr[node + 1];
        int deg = end - beg;
        const ushort* zrow = z + sl * 8;
        float a[8];
#pragma unroll
        for (int k = 0; k < 8; ++k) a[k] = 0.f;

        for (int base = 0; base < deg; base += 16) {
            int m = deg - base;
            if (m > 16) m = 16;
            int idx = (sl < m) ? adj[beg + base + sl] : 0;
#pragma unroll
            for (int half = 0; half < 2; ++half) {
                int mh = m - half * 8;
                if (mh <= 0) continue;
                if (mh > 8) mh = 8;
                int hb = half * 8;
                short8 v[8];
#pragma unroll
                for (int jj = 0; jj < 8; ++jj) {
                    int nj = __shfl(idx, hb + jj, 16);
                    if (jj < mh) v[jj] = *(const short8*)(zrow + (size_t)nj * H);
                }
                if (mh == 8) {
#pragma unroll
                    for (int k = 0; k < 8; ++k)
                        a[k] += ((bf2f((ushort)v[0][k]) + bf2f((ushort)v[1][k])) +
                                 (bf2f((ushort)v[2][k]) + bf2f((ushort)v[3][k]))) +
                                ((bf2f((ushort)v[4][k]) + bf2f((ushort)v[5][k])) +
                                 (bf2f((ushort)v[6][k]) + bf2f((ushort)v[7][k])));
                } else if (mh >= 4) {
#pragma unroll
                    for (int k = 0; k < 8; ++k)
                        a[k] += (bf2f((ushort)v[0][k]) + bf2f((ushort)v[1][k])) +
                                (bf2f((ushort)v[2][k]) + bf2f((ushort)v[3][k]));
                    if (mh > 4) {
#pragma unroll
                        for (int k = 0; k < 8; ++k) a[k] += bf2f((ushort)v[4][k]);
                    }
                    if (mh > 5) {
#pragma unroll
                        for (int k = 0; k < 8; ++k) a[k] += bf2f((ushort)v[5][k]);
                    }
                    if (mh > 6) {
#pragma unroll
                        for (int k = 0; k < 8; ++k) a[k] += bf2f((ushort)v[6][k]);
                    }
                } else {
                    if (mh > 0) {
#pragma unroll
                        for (int k = 0; k < 8; ++k) a[k] += bf2f((ushort)v[0][k]);
                    }
                    if (mh > 1) {
#pragma unroll
                        for (int k = 0; k < 8; ++k) a[k] += bf2f((ushort)v[1][k]);
                    }
                    if (mh > 2) {
#pragma unroll
                        for (int k = 0; k < 8; ++k) a[k] += bf2f((ushort)v[2][k]);
                    }
                }
            }
        }

        float inv = 1.0f / (float)(deg > 1 ? deg : 1);
        short8 yv = *(const short8*)(yb + (size_t)node * H + sl * 8);
        float4 bva = *(const float4*)(bl + sl * 8);
        float4 bvb = *(const float4*)(bl + sl * 8 + 4);
        float vv[8];
        vv[0] = a[0] * inv + bva.x + bf2f((ushort)yv[0]);
        vv[1] = a[1] * inv + bva.y + bf2f((ushort)yv[1]);
        vv[2] = a[2] * inv + bva.z + bf2f((ushort)yv[2]);
        vv[3] = a[3] * inv + bva.w + bf2f((ushort)yv[3]);
        vv[4] = a[4] * inv + bvb.x + bf2f((ushort)yv[4]);
        vv[5] = a[5] * inv + bvb.y + bf2f((ushort)yv[5]);
        vv[6] = a[6] * inv + bvb.z + bf2f((ushort)yv[6]);
        vv[7] = a[7] * inv + bvb.w + bf2f((ushort)yv[7]);
        {   // final layer norm=1
            float ss = 0.f;
#pragma unroll
            for (int k = 0; k < 8; ++k) ss += vv[k] * vv[k];
#pragma unroll
            for (int mm = 1; mm < 16; mm <<= 1) ss += __shfl_xor(ss, mm, 16);
            float n2 = 1.0f / fmaxf(sqrtf(ss), 1e-12f);
#pragma unroll
            for (int k = 0; k < 8; ++k) vv[k] *= n2;
        }
#pragma unroll
        for (int k = 0; k < 8; ++k) accs[nib][sl * 8 + k] = vv[k];
        if (sl == 0) gid[nib] = batch[node];
    } else {
        if (sl == 0) gid[nib] = -1;
    }
    __syncthreads();

    // column reduce: 128 threads, 16 serial adds, flush on graph change
    if (t < H) {
        int col = t;
        float run = 0.f;
        int cur = gid[0];                // node0 < N always (3125 blocks)
        for (int i = 0; i < 16; ++i) {
            int gg = gid[i];
            if (gg < 0) break;
            if (gg != cur) {
                atomicAdd(&g[(size_t)cur * H + col], run);
                run = 0.f; cur = gg;
            }
            run += accs[i][col];
        }
        atomicAdd(&g[(size_t)cur * H + col], run);
    }
}

// ---------------- MLP head ----------------

__global__ void k_mlp(const float* __restrict__ g, const float* __restrict__ W0,
                      const float* __restrict__ b0, const float* __restrict__ W1,
                      const float* __restrict__ b1, const float* __restrict__ Wh,
                      const float* __restrict__ bh, float* __restrict__ out) {
    int gi = blockIdx.x;
    int t  = threadIdx.x;  // 0..127
    __shared__ float buf0[H];
    __shared__ float buf1[H];
    __shared__ float red[2];

    float acc = b0[t];
    for (int k = 0; k < H; ++k) acc += g[gi * H + k] * W0[k * H + t];
    buf0[t] = fmaxf(acc, 0.f);
    __syncthreads();

    acc = b1[t];
    for (int k = 0; k < H; ++k) acc += buf0[k] * W1[k * H + t];
    buf1[t] = fmaxf(acc, 0.f);
    __syncthreads();

    float p = buf1[t] * Wh[t];
    for (int m = 1; m < 64; m <<= 1) p += __shfl_xor(p, m, 64);
    if ((t & 63) == 0) red[t >> 6] = p;
    __syncthreads();
    if (t == 0) out[gi] = red[0] + red[1] + bh[0];
}

// ---------------- driver ----------------

extern "C" void kernel_launch(void* const* d_in, const int* in_sizes, int n_in,
                              void* d_out, int out_size, void* d_ws, size_t ws_size,
                              hipStream_t stream) {
    const float* x     = (const float*)d_in[0];
    const int*   eic   = (const int*)d_in[1];
    const int*   eid   = (const int*)d_in[2];
    const int*   eit   = (const int*)d_in[3];
    const int*   batch = (const int*)d_in[4];
    const float* cW[5][3];
    for (int c = 0; c < 5; ++c) {
        cW[c][0] = (const float*)d_in[5 + c * 3 + 0];  // Wl
        cW[c][1] = (const float*)d_in[5 + c * 3 + 1];  // bl
        cW[c][2] = (const float*)d_in[5 + c * 3 + 2];  // Wr
    }
    const float* l0_W = (const float*)d_in[20];
    const float* l0_b = (const float*)d_in[21];
    const float* l1_W = (const float*)d_in[22];
    const float* l1_b = (const float*)d_in[23];
    const float* hd_W = (const float*)d_in[24];
    const float* hd_b = (const float*)d_in[25];
    float* outp = (float*)d_out;

    const size_t NH = (size_t)N_NODES * H;
    ushort* zb0 = (ushort*)d_ws;               // ping
    ushort* yb0 = zb0 + NH;
    ushort* zb1 = yb0 + NH;                    // pong
    ushort* yb1 = zb1 + NH;
    ushort* Bpk = yb1 + NH;                    // 5 convs x 2 planes x 32768
    float*  gbuf = (float*)(Bpk + 5 * 2 * 32768);
    int* gcnt = (int*)(gbuf + (size_t)NG * H);     // zeroed by k_prep
    int* rcnt = gcnt + NB;                         // zeroed by k_prep
    int* ptr_all = rcnt + NB;                      // N3+1 ints (persistent)
    int* adj_all = ptr_all + (N3 + 1);             // 3*NE ints (persistent)
    // CSR-build scratch inside zb0+yb0 (dead until gemm0, stream-ordered):
    //   bucket[NB*CAP2 int2] (64B-aligned at zb0) = 22.88 MB < 25.6MB
    int2* bucket = (int2*)zb0;

    dim3 b256(256);

    // prep: weight pre-scatter (blocks<640) + gbuf/gcnt/rcnt zeroing
    k_prep<<<dim3(640 + 34), b256, 0, stream>>>(
        (int*)gbuf,
        cW[0][0], cW[0][2], cW[1][0], cW[1][2], cW[2][0], cW[2][2],
        cW[3][0], cW[3][2], cW[4][0], cW[4][2], Bpk);

    // CSR build: bucketize -> per-bucket (total-scan + ptr + scatter)
    k_bucketize<<<dim3(3 * BPS), b256, 0, stream>>>(eic, eid, eit, gcnt, rcnt, bucket);
    k_scatter2<<<dim3(NB), dim3(512), 0, stream>>>(bucket, gcnt, rcnt, ptr_all, adj_all);

    const int L_set[7]  = {1, 0, 0, 2, 1, 0, 0};
    const int L_conv[7] = {0, 1, 1, 2, 3, 4, 4};
    const int L_norm[7] = {1, 1, 1, 0, 1, 1, 1};

    dim3 gGemm((N_NODES + 63) / 64);         // 782
    dim3 gFused((N_NODES + 31) / 32);        // 1563
    dim3 gAggP((N_NODES * 16 + 255) / 256);  // 3125 (final layer)

    // layer 1 GEMM directly from x -> pair0
    k_gemm0<<<gGemm, b256, 0, stream>>>(x, Bpk + (size_t)L_conv[0] * 65536,
                                        Bpk + (size_t)L_conv[0] * 65536 + 32768,
                                        zb0, yb0);

    // fused agg(L)+gemm(L+1), L=0..5, ping-pong z/y pairs
    for (int L = 0; L < 6; ++L) {
        ushort* zi = (L & 1) ? zb1 : zb0;
        ushort* yi = (L & 1) ? yb1 : yb0;
        ushort* zo = (L & 1) ? zb0 : zb1;
        ushort* yo = (L & 1) ? yb0 : yb1;
        const ushort* Bh = Bpk + (size_t)L_conv[L + 1] * 65536;
        const ushort* Bl = Bh + 32768;
        k_fused2<<<gFused, dim3(512), 0, stream>>>(zi, yi, zo, yo,
                                                   ptr_all + L_set[L] * N_NODES,
                                                   adj_all, cW[L_conv[L]][1], Bh, Bl,
                                                   L_norm[L]);
    }

    // final agg (L=6) reads pair0 (L=6 even) fused with global_add_pool
    k_aggpool<<<gAggP, b256, 0, stream>>>(zb0, yb0, ptr_all + L_set[6] * N_NODES,
                                          adj_all, cW[L_conv[6]][1], batch, gbuf);

    k_mlp<<<dim3(NG), dim3(H), 0, stream>>>(gbuf, l0_W, l0_b, l1_W, l1_b, hd_W, hd_b,
                                            outp);
}